// Round 1
// baseline (774.082 us; speedup 1.0000x reference)
//
#include <hip/hip_runtime.h>

typedef unsigned short ushort_t;
typedef unsigned int uint_t;
typedef __attribute__((ext_vector_type(8))) short s16x8;
typedef __attribute__((ext_vector_type(4))) float f32x4;

#define S_TOT 4096
#define EPSF 1e-5f
#define QSCALE 0.08838834764831845f   // 1/sqrt(128)
#define L2_10000_D16 0.8304820237218406f  // log2(10000)/16

__device__ inline ushort_t f2b(float f) {
  uint_t u = __float_as_uint(f);
  uint_t r = (u + 0x7FFFu + ((u >> 16) & 1u)) >> 16;
  return (ushort_t)r;
}

__device__ inline void store_row64(ushort_t* dst, const float* a) {
#pragma unroll
  for (int i = 0; i < 8; i++) {
    union { ushort_t u[8]; s16x8 v; } pk;
#pragma unroll
    for (int j = 0; j < 8; j++) pk.u[j] = f2b(a[i * 8 + j]);
    *(s16x8*)(dst + i * 8) = pk.v;
  }
}

// in-place 2D rope over a 64-vec (pairs), with optional extra scale
__device__ inline void rope64(float* v, int hi, int wi, float scale) {
#pragma unroll
  for (int k = 0; k < 32; k++) {
    int j = k >> 1;
    float inv = exp2f(-(float)j * L2_10000_D16);
    float ang = ((k & 1) ? (float)wi : (float)hi) * inv;
    float sn = sinf(ang), cs = cosf(ang);
    float x0 = v[2 * k], x1 = v[2 * k + 1];
    v[2 * k]     = (x0 * sn - x1 * cs) * scale;   // ref: rr = x0*f_sin - x1*f_cos
    v[2 * k + 1] = (x0 * cs + x1 * sn) * scale;   // ref: ri = x0*f_cos + x1*f_sin
  }
}

__device__ inline double wave_sum_d(double v) {
#pragma unroll
  for (int o = 1; o < 64; o <<= 1) v += __shfl_xor(v, o, 64);
  return v;
}

// ---------------------------------------------------------------------------
// K1: y_q = q1_w@x + q1_b (B,32,S); y_kv = kv1_w@x + kv1_b (B,128,S)
// + per-block double partial sums (sum, sumsq) for both tensors.
// grid B*64, block 256. block covers 64 s-positions, all 160 out channels.
__global__ __launch_bounds__(256) void k_conv1(
    const float* __restrict__ x, const float* __restrict__ q1_w, const float* __restrict__ q1_b,
    const float* __restrict__ kv1_w, const float* __restrict__ kv1_b,
    float* __restrict__ y_q, float* __restrict__ y_kv,
    double* __restrict__ pq, double* __restrict__ pkv) {
  const int b = blockIdx.x >> 6, blk = blockIdx.x & 63, st = blk * 64;
  const int t = threadIdx.x, si = t & 63, g = t >> 6;
  __shared__ float xs[128][64];
#pragma unroll
  for (int i = 0; i < 32; i++) {
    int c = g + 4 * i;
    xs[c][si] = x[(size_t)(b * 128 + c) * S_TOT + st + si];
  }
  __syncthreads();
  float acc[40];
#pragma unroll
  for (int i = 0; i < 40; i++) {
    int oc = g * 40 + i;
    acc[i] = (oc < 32) ? q1_b[oc] : kv1_b[oc - 32];
  }
  const float4* q1w4 = (const float4*)q1_w;
  const float4* kv1w4 = (const float4*)kv1_w;
  for (int c4 = 0; c4 < 32; c4++) {
    float x0 = xs[c4 * 4 + 0][si], x1 = xs[c4 * 4 + 1][si];
    float x2 = xs[c4 * 4 + 2][si], x3 = xs[c4 * 4 + 3][si];
#pragma unroll
    for (int i = 0; i < 40; i++) {
      int oc = g * 40 + i;
      float4 wv;
      if (oc < 32) wv = q1w4[oc * 32 + c4];
      else         wv = kv1w4[(oc - 32) * 32 + c4];
      acc[i] += wv.x * x0 + wv.y * x1 + wv.z * x2 + wv.w * x3;
    }
  }
  double sq = 0, sqq = 0, skv = 0, skvq = 0;
#pragma unroll
  for (int i = 0; i < 40; i++) {
    int oc = g * 40 + i;
    float a = acc[i];
    if (oc < 32) {
      y_q[(size_t)(b * 32 + oc) * S_TOT + st + si] = a;
      sq += a; sqq += (double)a * a;
    } else {
      y_kv[(size_t)(b * 128 + oc - 32) * S_TOT + st + si] = a;
      skv += a; skvq += (double)a * a;
    }
  }
  sq = wave_sum_d(sq); sqq = wave_sum_d(sqq);
  skv = wave_sum_d(skv); skvq = wave_sum_d(skvq);
  __shared__ double red[4][4];
  int lane = t & 63, wid = t >> 6;
  if (lane == 0) { red[wid][0] = sq; red[wid][1] = sqq; red[wid][2] = skv; red[wid][3] = skvq; }
  __syncthreads();
  if (t == 0) {
    double a = 0, bb = 0, c = 0, d = 0;
    for (int w = 0; w < 4; w++) { a += red[w][0]; bb += red[w][1]; c += red[w][2]; d += red[w][3]; }
    pq[(b * 64 + blk) * 2] = a;  pq[(b * 64 + blk) * 2 + 1] = bb;
    pkv[(b * 64 + blk) * 2] = c; pkv[(b * 64 + blk) * 2 + 1] = d;
  }
}

// ---------------------------------------------------------------------------
// K2: kv_gn = gn1(y_kv) materialized (B,128,S); partials of channels 64..127.
__global__ __launch_bounds__(256) void k_gnkv(
    const float* __restrict__ y_kv, const float* __restrict__ gn_g, const float* __restrict__ gn_b,
    const double* __restrict__ pkv, float* __restrict__ kv_gn, double* __restrict__ pkv2) {
  const int b = blockIdx.x >> 6, blk = blockIdx.x & 63, st = blk * 64;
  const int t = threadIdx.x, si = t & 63, g = t >> 6;
  double s = 0, ss = 0;
  for (int i = 0; i < 64; i++) { s += pkv[(b * 64 + i) * 2]; ss += pkv[(b * 64 + i) * 2 + 1]; }
  const double N = 128.0 * 4096.0;
  double mud = s / N, vard = ss / N - (s / N) * (s / N);
  float mu = (float)mud, rstd = rsqrtf((float)vard + EPSF);
  double l2s = 0, l2q = 0;
#pragma unroll
  for (int i = 0; i < 32; i++) {
    int c = g + 4 * i;
    size_t idx = (size_t)(b * 128 + c) * S_TOT + st + si;
    float v = y_kv[idx];
    float o = (v - mu) * rstd * gn_g[c] + gn_b[c];
    kv_gn[idx] = o;
    if (c >= 64) { l2s += o; l2q += (double)o * o; }
  }
  l2s = wave_sum_d(l2s); l2q = wave_sum_d(l2q);
  __shared__ double red[4][2];
  int lane = t & 63, wid = t >> 6;
  if (lane == 0) { red[wid][0] = l2s; red[wid][1] = l2q; }
  __syncthreads();
  if (t == 0) {
    double a = 0, bb = 0;
    for (int w = 0; w < 4; w++) { a += red[w][0]; bb += red[w][1]; }
    pkv2[(b * 64 + blk) * 2] = a; pkv2[(b * 64 + blk) * 2 + 1] = bb;
  }
}

// ---------------------------------------------------------------------------
// K3: Q build: q2 conv on normalized y_q, rope on dims 64..127, *QSCALE,
// store bf16 (B,H,S,128). grid B*64, block 256 (wave = one head, 64 s).
__global__ __launch_bounds__(256) void k_buildq(
    const float* __restrict__ y_q, const double* __restrict__ pq,
    const float* __restrict__ gn_g, const float* __restrict__ gn_b,
    const float* __restrict__ q2_w, const float* __restrict__ q2_b,
    ushort_t* __restrict__ Q) {
  const int b = blockIdx.x >> 6, blk = blockIdx.x & 63, st = blk * 64;
  const int t = threadIdx.x, si = t & 63, h = t >> 6;
  double s = 0, ss = 0;
  for (int i = 0; i < 64; i++) { s += pq[(b * 64 + i) * 2]; ss += pq[(b * 64 + i) * 2 + 1]; }
  const double N = 32.0 * 4096.0;
  double mud = s / N, vard = ss / N - (s / N) * (s / N);
  float mu = (float)mud, rstd = rsqrtf((float)vard + EPSF);
  __shared__ float qn[32][64];
#pragma unroll
  for (int i = 0; i < 8; i++) {
    int c = h + 4 * i;
    float v = y_q[(size_t)(b * 32 + c) * S_TOT + st + si];
    qn[c][si] = (v - mu) * rstd * gn_g[c] + gn_b[c];
  }
  __syncthreads();
  float qv[32];
#pragma unroll
  for (int c = 0; c < 32; c++) qv[c] = qn[c][si];
  const int sp = st + si, hi = sp >> 6, wi = sp & 63;
  ushort_t* qrow = Q + ((size_t)(b * 4 + h) * S_TOT + sp) * 128;
  const float4* w4 = (const float4*)q2_w;
  float acc[64];
  // chunk 0: nope dims 0..63 (scaled)
#pragma unroll
  for (int d = 0; d < 64; d++) {
    int oc = h * 128 + d;
    float a = q2_b[oc];
#pragma unroll
    for (int c4 = 0; c4 < 8; c4++) {
      float4 wv = w4[oc * 8 + c4];
      a += wv.x * qv[c4 * 4] + wv.y * qv[c4 * 4 + 1] + wv.z * qv[c4 * 4 + 2] + wv.w * qv[c4 * 4 + 3];
    }
    acc[d] = a * QSCALE;
  }
  store_row64(qrow, acc);
  // chunk 1: rope dims 64..127
#pragma unroll
  for (int d = 0; d < 64; d++) {
    int oc = h * 128 + 64 + d;
    float a = q2_b[oc];
#pragma unroll
    for (int c4 = 0; c4 < 8; c4++) {
      float4 wv = w4[oc * 8 + c4];
      a += wv.x * qv[c4 * 4] + wv.y * qv[c4 * 4 + 1] + wv.z * qv[c4 * 4 + 2] + wv.w * qv[c4 * 4 + 3];
    }
    acc[d] = a;
  }
  rope64(acc, hi, wi, QSCALE);
  store_row64(qrow + 64, acc);
}

// ---------------------------------------------------------------------------
// K4: KV build: kvup conv on gn'd kv_c -> k_nope + V; rope'd kv_gn[0:64] -> k_rope.
// K bf16 (B,H,S,128); V bf16 transposed (B,H,64,S). grid B*64, block 256.
__global__ __launch_bounds__(256) void k_buildkv(
    const float* __restrict__ kv_gn, const double* __restrict__ pkv2,
    const float* __restrict__ kvn_g, const float* __restrict__ kvn_b,
    const float* __restrict__ kvup_w, const float* __restrict__ kvup_b,
    ushort_t* __restrict__ K, ushort_t* __restrict__ VT) {
  const int b = blockIdx.x >> 6, blk = blockIdx.x & 63, st = blk * 64;
  const int t = threadIdx.x, si = t & 63, h = t >> 6;
  double s = 0, ss = 0;
  for (int i = 0; i < 64; i++) { s += pkv2[(b * 64 + i) * 2]; ss += pkv2[(b * 64 + i) * 2 + 1]; }
  const double N = 64.0 * 4096.0;
  double mud = s / N, vard = ss / N - (s / N) * (s / N);
  float mu = (float)mud, rstd = rsqrtf((float)vard + EPSF);
  __shared__ float kvn_s[64][64];
  __shared__ float kr_s[64][64];
#pragma unroll
  for (int i = 0; i < 16; i++) {
    int c = h + 4 * i;
    float v = kv_gn[(size_t)(b * 128 + 64 + c) * S_TOT + st + si];
    kvn_s[c][si] = (v - mu) * rstd * kvn_g[c] + kvn_b[c];
    kr_s[c][si] = kv_gn[(size_t)(b * 128 + c) * S_TOT + st + si];
  }
  __syncthreads();
  float kvv[64];
#pragma unroll
  for (int c = 0; c < 64; c++) kvv[c] = kvn_s[c][si];
  const int sp = st + si, hi = sp >> 6, wi = sp & 63;
  ushort_t* krow = K + ((size_t)(b * 4 + h) * S_TOT + sp) * 128;
  const float4* w4 = (const float4*)kvup_w;
  float acc[64];
  // k_nope: dims 0..63
#pragma unroll
  for (int d = 0; d < 64; d++) {
    int oc = h * 128 + d;
    float a = kvup_b[oc];
#pragma unroll
    for (int c4 = 0; c4 < 16; c4++) {
      float4 wv = w4[oc * 16 + c4];
      a += wv.x * kvv[c4 * 4] + wv.y * kvv[c4 * 4 + 1] + wv.z * kvv[c4 * 4 + 2] + wv.w * kvv[c4 * 4 + 3];
    }
    acc[d] = a;
  }
  store_row64(krow, acc);
  // v: dims 64..127 -> VT[b][h][vd][s]
#pragma unroll
  for (int d = 0; d < 64; d++) {
    int oc = h * 128 + 64 + d;
    float a = kvup_b[oc];
#pragma unroll
    for (int c4 = 0; c4 < 16; c4++) {
      float4 wv = w4[oc * 16 + c4];
      a += wv.x * kvv[c4 * 4] + wv.y * kvv[c4 * 4 + 1] + wv.z * kvv[c4 * 4 + 2] + wv.w * kvv[c4 * 4 + 3];
    }
    acc[d] = a;
  }
  ushort_t* vbase = VT + (size_t)(b * 4 + h) * 64 * S_TOT + sp;
#pragma unroll
  for (int d = 0; d < 64; d++) vbase[(size_t)d * S_TOT] = f2b(acc[d]);
  // k_rope (shared across heads; each head-wave recomputes for its copy)
  float kr[64];
#pragma unroll
  for (int c = 0; c < 64; c++) kr[c] = kr_s[c][si];
  rope64(kr, hi, wi, 1.0f);
  store_row64(krow + 64, kr);
}

// ---------------------------------------------------------------------------
// K5: flash attention. grid = B*H*64 blocks, 4 waves/block, 16 q-rows/wave.
// KV step = 32. mfma_f32_16x16x32_bf16. O (B,H,S,64) f32.
__global__ __launch_bounds__(256) void k_attn(
    const ushort_t* __restrict__ Q, const ushort_t* __restrict__ K,
    const ushort_t* __restrict__ VT, float* __restrict__ O) {
  const int bh = blockIdx.x >> 6, qblk = blockIdx.x & 63;
  const int wid = threadIdx.x >> 6, lane = threadIdx.x & 63;
  const int l15 = lane & 15, lg = lane >> 4;
  const int qbase = qblk * 64 + wid * 16;
  const ushort_t* Qp = Q + (size_t)bh * S_TOT * 128;
  const ushort_t* Kp = K + (size_t)bh * S_TOT * 128;
  const ushort_t* Vp = VT + (size_t)bh * 64 * S_TOT;
  __shared__ __align__(16) ushort_t P_lds[4][16][32];

  s16x8 qa[4];
#pragma unroll
  for (int kk = 0; kk < 4; kk++)
    qa[kk] = *(const s16x8*)(Qp + ((size_t)(qbase + l15)) * 128 + kk * 32 + lg * 8);

  f32x4 o_acc[4];
#pragma unroll
  for (int n = 0; n < 4; n++) o_acc[n] = (f32x4){0.f, 0.f, 0.f, 0.f};
  float m[4], l[4];
#pragma unroll
  for (int r = 0; r < 4; r++) { m[r] = -1e30f; l[r] = 0.f; }

#pragma unroll 1
  for (int kv = 0; kv < S_TOT; kv += 32) {
    f32x4 sc[2];
    sc[0] = (f32x4){0.f, 0.f, 0.f, 0.f};
    sc[1] = (f32x4){0.f, 0.f, 0.f, 0.f};
#pragma unroll
    for (int cb = 0; cb < 2; cb++) {
#pragma unroll
      for (int kk = 0; kk < 4; kk++) {
        s16x8 kf = *(const s16x8*)(Kp + ((size_t)(kv + cb * 16 + l15)) * 128 + kk * 32 + lg * 8);
        sc[cb] = __builtin_amdgcn_mfma_f32_16x16x32_bf16(qa[kk], kf, sc[cb], 0, 0, 0);
      }
    }
    // online softmax update (rows = lg*4+r, cols across 16-lane group x 2 col blocks)
    float alpha[4];
#pragma unroll
    for (int r = 0; r < 4; r++) {
      float v = fmaxf(sc[0][r], sc[1][r]);
      v = fmaxf(v, __shfl_xor(v, 1, 16));
      v = fmaxf(v, __shfl_xor(v, 2, 16));
      v = fmaxf(v, __shfl_xor(v, 4, 16));
      v = fmaxf(v, __shfl_xor(v, 8, 16));
      float mn = fmaxf(m[r], v);
      alpha[r] = __expf(m[r] - mn);
      m[r] = mn;
    }
#pragma unroll
    for (int r = 0; r < 4; r++) {
      float p0 = __expf(sc[0][r] - m[r]);
      float p1 = __expf(sc[1][r] - m[r]);
      sc[0][r] = p0; sc[1][r] = p1;
      float rs = p0 + p1;
      rs += __shfl_xor(rs, 1, 16);
      rs += __shfl_xor(rs, 2, 16);
      rs += __shfl_xor(rs, 4, 16);
      rs += __shfl_xor(rs, 8, 16);
      l[r] = l[r] * alpha[r] + rs;
    }
    // rescale O
#pragma unroll
    for (int n = 0; n < 4; n++)
#pragma unroll
      for (int r = 0; r < 4; r++) o_acc[n][r] *= alpha[r];
    // P -> LDS (D layout) then reload as A-frag
#pragma unroll
    for (int cb = 0; cb < 2; cb++)
#pragma unroll
      for (int r = 0; r < 4; r++)
        P_lds[wid][lg * 4 + r][cb * 16 + l15] = f2b(sc[cb][r]);
    s16x8 pa = *(const s16x8*)&P_lds[wid][l15][lg * 8];
#pragma unroll
    for (int n = 0; n < 4; n++) {
      s16x8 vb = *(const s16x8*)(Vp + ((size_t)(n * 16 + l15)) * S_TOT + kv + lg * 8);
      o_acc[n] = __builtin_amdgcn_mfma_f32_16x16x32_bf16(pa, vb, o_acc[n], 0, 0, 0);
    }
  }
  float invl[4];
#pragma unroll
  for (int r = 0; r < 4; r++) invl[r] = 1.f / l[r];
#pragma unroll
  for (int n = 0; n < 4; n++)
#pragma unroll
    for (int r = 0; r < 4; r++)
      O[((size_t)bh * S_TOT + qbase + lg * 4 + r) * 64 + n * 16 + l15] = o_acc[n][r] * invl[r];
}

// ---------------------------------------------------------------------------
// K6: out conv + residual. grid B*128 (32 s per block), block 256.
__global__ __launch_bounds__(256) void k_outconv(
    const float* __restrict__ O, const float* __restrict__ out_w, const float* __restrict__ out_b,
    const float* __restrict__ x, float* __restrict__ out) {
  const int b = blockIdx.x >> 7, blk = blockIdx.x & 127, st = blk * 32;
  const int t = threadIdx.x;
  __shared__ float o_lds[256][33];
  {
    int vd = t & 63, r0 = t >> 6;
#pragma unroll
    for (int i = 0; i < 32; i++) {
      int hs = r0 + 4 * i;          // 0..127 = (h, s)
      int h = hs >> 5, ss2 = hs & 31;
      o_lds[h * 64 + vd][ss2] = O[((size_t)(b * 4 + h) * S_TOT + st + ss2) * 64 + vd];
    }
  }
  __syncthreads();
  const int si = t & 31, g = t >> 5;   // 8 channel groups
  const float4* w4 = (const float4*)out_w;
#pragma unroll
  for (int i = 0; i < 16; i++) {
    int c = g + 8 * i;
    float a = out_b[c];
#pragma unroll 8
    for (int hv4 = 0; hv4 < 64; hv4++) {
      float4 wv = w4[c * 64 + hv4];
      a += wv.x * o_lds[hv4 * 4 + 0][si] + wv.y * o_lds[hv4 * 4 + 1][si]
         + wv.z * o_lds[hv4 * 4 + 2][si] + wv.w * o_lds[hv4 * 4 + 3][si];
    }
    size_t idx = (size_t)(b * 128 + c) * S_TOT + st + si;
    out[idx] = a + x[idx];
  }
}

// ---------------------------------------------------------------------------
extern "C" void kernel_launch(void* const* d_in, const int* in_sizes, int n_in,
                              void* d_out, int out_size, void* d_ws, size_t ws_size,
                              hipStream_t stream) {
  const float* x      = (const float*)d_in[0];
  const float* q1_w   = (const float*)d_in[1];
  const float* q1_b   = (const float*)d_in[2];
  const float* q_gn_g = (const float*)d_in[3];
  const float* q_gn_b = (const float*)d_in[4];
  const float* q2_w   = (const float*)d_in[5];
  const float* q2_b   = (const float*)d_in[6];
  const float* kv1_w  = (const float*)d_in[7];
  const float* kv1_b  = (const float*)d_in[8];
  const float* kv_gn_g= (const float*)d_in[9];
  const float* kv_gn_b= (const float*)d_in[10];
  const float* kvn_g  = (const float*)d_in[11];
  const float* kvn_b  = (const float*)d_in[12];
  const float* kvup_w = (const float*)d_in[13];
  const float* kvup_b = (const float*)d_in[14];
  const float* out_w  = (const float*)d_in[15];
  const float* out_b  = (const float*)d_in[16];

  char* ws = (char*)d_ws;
  float*    y_q   = (float*)(ws);                          // 1 MB
  float*    y_kv  = (float*)(ws + (size_t)1  * (1u << 20)); // 4 MB
  float*    kv_gn = (float*)(ws + (size_t)5  * (1u << 20)); // 4 MB
  ushort_t* Q     = (ushort_t*)(ws + (size_t)9  * (1u << 20)); // 8 MB
  ushort_t* K     = (ushort_t*)(ws + (size_t)17 * (1u << 20)); // 8 MB
  ushort_t* VT    = (ushort_t*)(ws + (size_t)25 * (1u << 20)); // 4 MB
  float*    O     = (float*)(ws + (size_t)29 * (1u << 20));    // 8 MB
  double*   pq    = (double*)(ws + (size_t)37 * (1u << 20));   // 128 doubles
  double*   pkv   = pq + 256;
  double*   pkv2  = pkv + 256;
  float*    out   = (float*)d_out;

  k_conv1  <<<128, 256, 0, stream>>>(x, q1_w, q1_b, kv1_w, kv1_b, y_q, y_kv, pq, pkv);
  k_gnkv   <<<128, 256, 0, stream>>>(y_kv, kv_gn_g, kv_gn_b, pkv, kv_gn, pkv2);
  k_buildq <<<128, 256, 0, stream>>>(y_q, pq, q_gn_g, q_gn_b, q2_w, q2_b, Q);
  k_buildkv<<<128, 256, 0, stream>>>(kv_gn, pkv2, kvn_g, kvn_b, kvup_w, kvup_b, K, VT);
  k_attn   <<<512, 256, 0, stream>>>(Q, K, VT, O);
  k_outconv<<<256, 256, 0, stream>>>(O, out_w, out_b, x, out);
}

// Round 2
// 418.326 us; speedup vs baseline: 1.8504x; 1.8504x over previous
//
#include <hip/hip_runtime.h>

typedef unsigned short ushort_t;
typedef unsigned int uint_t;
typedef __attribute__((ext_vector_type(8))) short s16x8;
typedef __attribute__((ext_vector_type(4))) float f32x4;

#define S_TOT 4096
#define QSCALE 0.08838834764831845f   // 1/sqrt(128)
#define L2_10000_D16 0.8304820237218406f  // log2(10000)/16

__device__ __forceinline__ ushort_t f2b(float f) {
  uint_t u = __float_as_uint(f);
  uint_t r = (u + 0x7FFFu + ((u >> 16) & 1u)) >> 16;
  return (ushort_t)r;
}

template <int N8>
__device__ __forceinline__ void store_rowN(ushort_t* dst, const float* a) {
#pragma unroll
  for (int i = 0; i < N8; i++) {
    union { ushort_t u[8]; s16x8 v; } pk;
#pragma unroll
    for (int j = 0; j < 8; j++) pk.u[j] = f2b(a[i * 8 + j]);
    *(s16x8*)(dst + i * 8) = pk.v;
  }
}

// in-place 2D rope over a 64-vec (pairs), with extra scale
__device__ __forceinline__ void rope64(float* v, int hi, int wi, float scale) {
#pragma unroll
  for (int k = 0; k < 32; k++) {
    int j = k >> 1;
    float inv = exp2f(-(float)j * L2_10000_D16);
    float ang = ((k & 1) ? (float)wi : (float)hi) * inv;
    float sn = sinf(ang), cs = cosf(ang);
    float x0 = v[2 * k], x1 = v[2 * k + 1];
    v[2 * k]     = (x0 * sn - x1 * cs) * scale;
    v[2 * k + 1] = (x0 * cs + x1 * sn) * scale;
  }
}

__device__ __forceinline__ void gload16(const void* g, void* l) {
  __builtin_amdgcn_global_load_lds(
      (const __attribute__((address_space(1))) unsigned int*)g,
      (__attribute__((address_space(3))) unsigned int*)l, 16, 0, 0);
}

// ---------------------------------------------------------------------------
// K1: y_q = q1_w@x + b (B,32,S); y_kv = kv1_w@x + b (B,128,S)
// + per-channel per-block partial (sum, sumsq) in double -> pch[b][blk][160][2]
// grid B*128 (32 s per block), block 256: si=t&31, g=t>>5 (8 groups x 20 ch)
__global__ __launch_bounds__(256) void k_conv1(
    const float* __restrict__ x, const float* __restrict__ q1_w, const float* __restrict__ q1_b,
    const float* __restrict__ kv1_w, const float* __restrict__ kv1_b,
    float* __restrict__ y_q, float* __restrict__ y_kv, double* __restrict__ pch) {
  const int b = blockIdx.x >> 7, blk = blockIdx.x & 127, st = blk * 32;
  const int t = threadIdx.x, si = t & 31, g = t >> 5;
  __shared__ float xs[128][32];
#pragma unroll
  for (int i = 0; i < 16; i++) {
    int c = g + 8 * i;
    xs[c][si] = x[(size_t)(b * 128 + c) * S_TOT + st + si];
  }
  __syncthreads();
  float acc[20];
#pragma unroll
  for (int i = 0; i < 20; i++) {
    int oc = g * 20 + i;
    acc[i] = (oc < 32) ? q1_b[oc] : kv1_b[oc - 32];
  }
  const float4* q1w4 = (const float4*)q1_w;
  const float4* kv1w4 = (const float4*)kv1_w;
  for (int c4 = 0; c4 < 32; c4++) {
    float x0 = xs[c4 * 4 + 0][si], x1 = xs[c4 * 4 + 1][si];
    float x2 = xs[c4 * 4 + 2][si], x3 = xs[c4 * 4 + 3][si];
#pragma unroll
    for (int i = 0; i < 20; i++) {
      int oc = g * 20 + i;
      float4 wv = (oc < 32) ? q1w4[oc * 32 + c4] : kv1w4[(oc - 32) * 32 + c4];
      acc[i] += wv.x * x0 + wv.y * x1 + wv.z * x2 + wv.w * x3;
    }
  }
  double* pbase = pch + (size_t)(b * 128 + blk) * 160 * 2;
#pragma unroll
  for (int i = 0; i < 20; i++) {
    int oc = g * 20 + i;
    float a = acc[i];
    if (oc < 32) y_q[(size_t)(b * 32 + oc) * S_TOT + st + si] = a;
    else         y_kv[(size_t)(b * 128 + oc - 32) * S_TOT + st + si] = a;
    double s = a, q = (double)a * a;
#pragma unroll
    for (int o = 1; o < 32; o <<= 1) { s += __shfl_xor(s, o, 32); q += __shfl_xor(q, o, 32); }
    if (si == 0) { pbase[oc * 2] = s; pbase[oc * 2 + 1] = q; }
  }
}

// ---------------------------------------------------------------------------
// K2: reduce partials, compose both group-norms analytically into per-channel
// affine coefs. coef per b (320 floats): [qA 0..31 | qB 32..63 | krA 64..127 |
// krB 128..191 | kvnA 192..255 | kvnB 256..319]
__global__ __launch_bounds__(256) void k_stats(
    const double* __restrict__ pch,
    const float* __restrict__ qg, const float* __restrict__ qb,
    const float* __restrict__ kvg, const float* __restrict__ kvb,
    const float* __restrict__ kng, const float* __restrict__ knb,
    float* __restrict__ coef) {
  __shared__ double Sh[2][160], Qh[2][160];
  for (int idx = threadIdx.x; idx < 320; idx += 256) {
    int b = idx / 160, c = idx % 160;
    double s = 0, q = 0;
    for (int blkk = 0; blkk < 128; blkk++) {
      const double* p = pch + ((size_t)(b * 128 + blkk) * 160 + c) * 2;
      s += p[0]; q += p[1];
    }
    Sh[b][c] = s; Qh[b][c] = q;
  }
  __syncthreads();
  if (threadIdx.x < 2) {
    int b = threadIdx.x;
    float* cf = coef + b * 320;
    const double NS = 4096.0;
    // q gn (32 ch)
    double muq = 0, m2q = 0;
    for (int c = 0; c < 32; c++) { muq += Sh[b][c]; m2q += Qh[b][c]; }
    muq /= (32.0 * NS); m2q /= (32.0 * NS);
    double rstdq = 1.0 / sqrt(m2q - muq * muq + 1e-5);
    for (int c = 0; c < 32; c++) {
      double A = rstdq * (double)qg[c];
      cf[c] = (float)A; cf[32 + c] = (float)((double)qb[c] - muq * A);
    }
    // kv gn (128 ch; pch index 32+c)
    double mukv = 0, m2kv = 0;
    for (int c = 0; c < 128; c++) { mukv += Sh[b][32 + c]; m2kv += Qh[b][32 + c]; }
    mukv /= (128.0 * NS); m2kv /= (128.0 * NS);
    double rstdkv = 1.0 / sqrt(m2kv - mukv * mukv + 1e-5);
    for (int c = 0; c < 64; c++) {  // rope channels 0..63
      double A = rstdkv * (double)kvg[c];
      cf[64 + c] = (float)A; cf[128 + c] = (float)((double)kvb[c] - mukv * A);
    }
    // nested gn over gn'd kv channels 64..127: stats of affine transform
    double mu2 = 0, m22 = 0;
    for (int c2 = 0; c2 < 64; c2++) {
      int c = 64 + c2;
      double a = rstdkv * (double)kvg[c], bb = (double)kvb[c] - mukv * a;
      double Ec = Sh[b][32 + c] / NS, M2c = Qh[b][32 + c] / NS;
      mu2 += a * Ec + bb;
      m22 += a * a * M2c + 2.0 * a * bb * Ec + bb * bb;
    }
    mu2 /= 64.0; m22 /= 64.0;
    double rstd2 = 1.0 / sqrt(m22 - mu2 * mu2 + 1e-5);
    for (int c2 = 0; c2 < 64; c2++) {
      int c = 64 + c2;
      double a = rstdkv * (double)kvg[c], bb = (double)kvb[c] - mukv * a;
      cf[192 + c2] = (float)(a * rstd2 * (double)kng[c2]);
      cf[256 + c2] = (float)((bb - mu2) * rstd2 * (double)kng[c2] + (double)knb[c2]);
    }
  }
}

// ---------------------------------------------------------------------------
// K3: Q build. grid B*64*2 (chunk: 0=nope d0..63, 1=rope d64..127), block 256,
// wave = head, si = lane (64 s per block).
__global__ __launch_bounds__(256) void k_buildq(
    const float* __restrict__ y_q, const float* __restrict__ coef,
    const float* __restrict__ q2_w, const float* __restrict__ q2_b,
    ushort_t* __restrict__ Q) {
  int id = blockIdx.x;
  const int chunk = id & 1; id >>= 1;
  const int b = id >> 6, blk = id & 63, st = blk * 64;
  const int t = threadIdx.x, si = t & 63, h = t >> 6;
  const float* cf = coef + b * 320;
  __shared__ float qn[32][64];
#pragma unroll
  for (int i = 0; i < 8; i++) {
    int c = h + 4 * i;
    float v = y_q[(size_t)(b * 32 + c) * S_TOT + st + si];
    qn[c][si] = v * cf[c] + cf[32 + c];
  }
  __syncthreads();
  float qv[32];
#pragma unroll
  for (int c = 0; c < 32; c++) qv[c] = qn[c][si];
  const int sp = st + si, hi = sp >> 6, wi = sp & 63;
  ushort_t* qrow = Q + ((size_t)(b * 4 + h) * S_TOT + sp) * 128;
  const float4* w4 = (const float4*)q2_w;
  float acc[64];
#pragma unroll
  for (int d = 0; d < 64; d++) {
    int oc = h * 128 + chunk * 64 + d;
    float a = q2_b[oc];
#pragma unroll
    for (int c4 = 0; c4 < 8; c4++) {
      float4 wv = w4[oc * 8 + c4];
      a += wv.x * qv[c4 * 4] + wv.y * qv[c4 * 4 + 1] + wv.z * qv[c4 * 4 + 2] + wv.w * qv[c4 * 4 + 3];
    }
    acc[d] = a;
  }
  if (chunk == 0) {
#pragma unroll
    for (int d = 0; d < 64; d++) acc[d] *= QSCALE;
  } else {
    rope64(acc, hi, wi, QSCALE);
  }
  store_rowN<8>(qrow + chunk * 64, acc);
}

// ---------------------------------------------------------------------------
// K4: KV build. grid B*64*5. chunks 0,1: k_nope d0..31/d32..63; 2,3: v halves;
// 4: k_rope. block 256, wave = head, si = lane.
__global__ __launch_bounds__(256) void k_buildkv(
    const float* __restrict__ y_kv, const float* __restrict__ coef,
    const float* __restrict__ kvup_w, const float* __restrict__ kvup_b,
    ushort_t* __restrict__ K, ushort_t* __restrict__ VT) {
  int id = blockIdx.x;
  const int chunk = id % 5; id /= 5;
  const int b = id >> 6, blk = id & 63, st = blk * 64;
  const int t = threadIdx.x, si = t & 63, h = t >> 6;
  const float* cf = coef + b * 320;
  const int sp = st + si;
  ushort_t* krow = K + ((size_t)(b * 4 + h) * S_TOT + sp) * 128;
  __shared__ float tile[64][64];
  if (chunk == 4) {
    // k_rope: channels 0..63 with kr affine, rope, store to dims 64..127
#pragma unroll
    for (int i = 0; i < 16; i++) {
      int c = h + 4 * i;
      float v = y_kv[(size_t)(b * 128 + c) * S_TOT + st + si];
      tile[c][si] = v * cf[64 + c] + cf[128 + c];
    }
    __syncthreads();
    float kr[64];
#pragma unroll
    for (int c = 0; c < 64; c++) kr[c] = tile[c][si];
    rope64(kr, sp >> 6, sp & 63, 1.0f);
    store_rowN<8>(krow + 64, kr);
    return;
  }
  // conv chunks: normalized kv_c (channels 64..127 with composed affine)
#pragma unroll
  for (int i = 0; i < 16; i++) {
    int c = h + 4 * i;
    float v = y_kv[(size_t)(b * 128 + 64 + c) * S_TOT + st + si];
    tile[c][si] = v * cf[192 + c] + cf[256 + c];
  }
  __syncthreads();
  float kvv[64];
#pragma unroll
  for (int c = 0; c < 64; c++) kvv[c] = tile[c][si];
  const int vsel = chunk >> 1, dh = (chunk & 1) * 32;
  const float4* w4 = (const float4*)kvup_w;
  float acc[32];
#pragma unroll
  for (int d = 0; d < 32; d++) {
    int oc = h * 128 + vsel * 64 + dh + d;
    float a = kvup_b[oc];
#pragma unroll
    for (int c4 = 0; c4 < 16; c4++) {
      float4 wv = w4[oc * 16 + c4];
      a += wv.x * kvv[c4 * 4] + wv.y * kvv[c4 * 4 + 1] + wv.z * kvv[c4 * 4 + 2] + wv.w * kvv[c4 * 4 + 3];
    }
    acc[d] = a;
  }
  if (vsel == 0) {
    store_rowN<4>(krow + dh, acc);
  } else {
    ushort_t* vbase = VT + (size_t)(b * 4 + h) * 64 * S_TOT + sp;
#pragma unroll
    for (int d = 0; d < 32; d++) vbase[(size_t)(dh + d) * S_TOT] = f2b(acc[d]);
  }
}

// ---------------------------------------------------------------------------
// K5: flash attention, KV tile 64, LDS-staged K+V double-buffered via
// global_load_lds with XOR-swizzled global source (m173 pattern).
// grid B*H*64, block 256 = 4 waves x 16 q-rows.
__global__ __launch_bounds__(256) void k_attn(
    const ushort_t* __restrict__ Q, const ushort_t* __restrict__ K,
    const ushort_t* __restrict__ VT, float* __restrict__ O) {
  const int bh = blockIdx.x >> 6, qblk = blockIdx.x & 63;
  const int tid = threadIdx.x;
  const int wid = tid >> 6, lane = tid & 63;
  const int l15 = lane & 15, lg = lane >> 4;
  const int qbase = qblk * 64 + wid * 16;
  const ushort_t* Qp = Q + (size_t)bh * S_TOT * 128;
  const ushort_t* Kp = K + (size_t)bh * S_TOT * 128;
  const ushort_t* Vp = VT + (size_t)bh * 64 * S_TOT;

  __shared__ __align__(16) ushort_t K_lds[2][64][128];  // 2 x 16 KB
  __shared__ __align__(16) ushort_t V_lds[2][64][64];   // 2 x 8 KB
  __shared__ __align__(16) ushort_t P_lds[4][16][64];   // 8 KB

  s16x8 qa[4];
#pragma unroll
  for (int kk = 0; kk < 4; kk++)
    qa[kk] = *(const s16x8*)(Qp + (size_t)(qbase + l15) * 128 + kk * 32 + lg * 8);

  f32x4 o_acc[4];
#pragma unroll
  for (int n = 0; n < 4; n++) o_acc[n] = (f32x4){0.f, 0.f, 0.f, 0.f};
  float m[4], l[4];
#pragma unroll
  for (int r = 0; r < 4; r++) { m[r] = -1e30f; l[r] = 0.f; }

  // staging lane constants
  const int krow_l = wid * 4 + (lane >> 4);          // + i*16
  const int kcol_l = (lane & 15) * 16;
  const int vrow_l = wid * 8 + (lane >> 3);          // + i*32
  const int vcol_l = (lane & 7) * 16;

#define STAGE(kvb, bufi)                                                          \
  {                                                                               \
    _Pragma("unroll")                                                             \
    for (int i = 0; i < 4; i++) {                                                 \
      int row = i * 16 + krow_l;                                                  \
      int colb = kcol_l ^ ((row & 7) << 4);                                       \
      gload16((const char*)(Kp + (size_t)((kvb) + row) * 128) + colb,             \
              (void*)&K_lds[bufi][i * 16 + wid * 4][0]);                          \
    }                                                                             \
    _Pragma("unroll")                                                             \
    for (int i = 0; i < 2; i++) {                                                 \
      int vd = i * 32 + vrow_l;                                                   \
      int colb = vcol_l ^ ((vd & 7) << 4);                                        \
      gload16((const char*)(Vp + (size_t)vd * S_TOT + (kvb)) + colb,              \
              (void*)&V_lds[bufi][i * 32 + wid * 8][0]);                          \
    }                                                                             \
  }

  STAGE(0, 0);
  __syncthreads();

  const int swz = (l15 & 7) << 4;
#pragma unroll 1
  for (int t = 0; t < 64; t++) {
    const int buf = t & 1;
    if (t < 63) STAGE((t + 1) * 64, buf ^ 1);
    // QK^T: sc[cb] cols cb*16+l15, rows lg*4+r
    f32x4 sc[4];
#pragma unroll
    for (int cb = 0; cb < 4; cb++) sc[cb] = (f32x4){0.f, 0.f, 0.f, 0.f};
#pragma unroll
    for (int kk = 0; kk < 4; kk++) {
#pragma unroll
      for (int cb = 0; cb < 4; cb++) {
        const int row = cb * 16 + l15;
        const int off = (kk * 64 + lg * 16) ^ swz;
        s16x8 kf = *(const s16x8*)((const char*)&K_lds[buf][row][0] + off);
        sc[cb] = __builtin_amdgcn_mfma_f32_16x16x32_bf16(qa[kk], kf, sc[cb], 0, 0, 0);
      }
    }
    // online softmax
    float alpha[4];
#pragma unroll
    for (int r = 0; r < 4; r++) {
      float v = fmaxf(fmaxf(sc[0][r], sc[1][r]), fmaxf(sc[2][r], sc[3][r]));
      v = fmaxf(v, __shfl_xor(v, 1, 16));
      v = fmaxf(v, __shfl_xor(v, 2, 16));
      v = fmaxf(v, __shfl_xor(v, 4, 16));
      v = fmaxf(v, __shfl_xor(v, 8, 16));
      float mn = fmaxf(m[r], v);
      alpha[r] = __expf(m[r] - mn);
      m[r] = mn;
    }
#pragma unroll
    for (int r = 0; r < 4; r++) {
      float rs = 0.f;
#pragma unroll
      for (int cb = 0; cb < 4; cb++) {
        float p = __expf(sc[cb][r] - m[r]);
        sc[cb][r] = p; rs += p;
      }
      rs += __shfl_xor(rs, 1, 16);
      rs += __shfl_xor(rs, 2, 16);
      rs += __shfl_xor(rs, 4, 16);
      rs += __shfl_xor(rs, 8, 16);
      l[r] = l[r] * alpha[r] + rs;
    }
#pragma unroll
    for (int n = 0; n < 4; n++)
#pragma unroll
      for (int r = 0; r < 4; r++) o_acc[n][r] *= alpha[r];
    // P -> LDS (swizzled), reload as A-frags
#pragma unroll
    for (int cb = 0; cb < 4; cb++)
#pragma unroll
      for (int r = 0; r < 4; r++) {
        const int row = lg * 4 + r;
        const int off = ((cb * 16 + l15) * 2) ^ ((row & 7) << 4);
        *(ushort_t*)((char*)&P_lds[wid][row][0] + off) = f2b(sc[cb][r]);
      }
    asm volatile("s_waitcnt lgkmcnt(0)" ::: "memory");
    __builtin_amdgcn_sched_barrier(0);
#pragma unroll
    for (int ks = 0; ks < 2; ks++) {
      const int off = (ks * 64 + lg * 16) ^ swz;
      s16x8 pa = *(const s16x8*)((const char*)&P_lds[wid][l15][0] + off);
#pragma unroll
      for (int n = 0; n < 4; n++) {
        s16x8 vb = *(const s16x8*)((const char*)&V_lds[buf][n * 16 + l15][0] + off);
        o_acc[n] = __builtin_amdgcn_mfma_f32_16x16x32_bf16(pa, vb, o_acc[n], 0, 0, 0);
      }
    }
    __syncthreads();
  }
#undef STAGE
  float invl[4];
#pragma unroll
  for (int r = 0; r < 4; r++) invl[r] = 1.f / l[r];
#pragma unroll
  for (int n = 0; n < 4; n++)
#pragma unroll
    for (int r = 0; r < 4; r++)
      O[((size_t)bh * S_TOT + qbase + lg * 4 + r) * 64 + n * 16 + l15] = o_acc[n][r] * invl[r];
}

// ---------------------------------------------------------------------------
// K6: out conv + residual. grid B*128*2 (chunk over 64 out-channels), block 256.
__global__ __launch_bounds__(256) void k_outconv(
    const float* __restrict__ O, const float* __restrict__ out_w, const float* __restrict__ out_b,
    const float* __restrict__ x, float* __restrict__ out) {
  int id = blockIdx.x;
  const int chunk = id & 1; id >>= 1;
  const int b = id >> 7, blk = id & 127, st = blk * 32;
  const int t = threadIdx.x;
  __shared__ float o_lds[256][33];
  {
    int vd = t & 63, r0 = t >> 6;
#pragma unroll
    for (int i = 0; i < 32; i++) {
      int hs = r0 + 4 * i;
      int h = hs >> 5, ss2 = hs & 31;
      o_lds[h * 64 + vd][ss2] = O[((size_t)(b * 4 + h) * S_TOT + st + ss2) * 64 + vd];
    }
  }
  __syncthreads();
  const int si = t & 31, g = t >> 5;
  const float4* w4 = (const float4*)out_w;
#pragma unroll
  for (int i = 0; i < 8; i++) {
    int c = chunk * 64 + g + 8 * i;
    float a = out_b[c];
#pragma unroll 8
    for (int hv4 = 0; hv4 < 64; hv4++) {
      float4 wv = w4[c * 64 + hv4];
      a += wv.x * o_lds[hv4 * 4 + 0][si] + wv.y * o_lds[hv4 * 4 + 1][si]
         + wv.z * o_lds[hv4 * 4 + 2][si] + wv.w * o_lds[hv4 * 4 + 3][si];
    }
    size_t idx = (size_t)(b * 128 + c) * S_TOT + st + si;
    out[idx] = a + x[idx];
  }
}

// ---------------------------------------------------------------------------
extern "C" void kernel_launch(void* const* d_in, const int* in_sizes, int n_in,
                              void* d_out, int out_size, void* d_ws, size_t ws_size,
                              hipStream_t stream) {
  const float* x      = (const float*)d_in[0];
  const float* q1_w   = (const float*)d_in[1];
  const float* q1_b   = (const float*)d_in[2];
  const float* q_gn_g = (const float*)d_in[3];
  const float* q_gn_b = (const float*)d_in[4];
  const float* q2_w   = (const float*)d_in[5];
  const float* q2_b   = (const float*)d_in[6];
  const float* kv1_w  = (const float*)d_in[7];
  const float* kv1_b  = (const float*)d_in[8];
  const float* kv_gn_g= (const float*)d_in[9];
  const float* kv_gn_b= (const float*)d_in[10];
  const float* kvn_g  = (const float*)d_in[11];
  const float* kvn_b  = (const float*)d_in[12];
  const float* kvup_w = (const float*)d_in[13];
  const float* kvup_b = (const float*)d_in[14];
  const float* out_w  = (const float*)d_in[15];
  const float* out_b  = (const float*)d_in[16];

  char* ws = (char*)d_ws;
  float*    y_q  = (float*)(ws);                              // 1 MB
  float*    y_kv = (float*)(ws + (size_t)1  * (1u << 20));    // 4 MB
  ushort_t* Q    = (ushort_t*)(ws + (size_t)5  * (1u << 20)); // 8 MB
  ushort_t* K    = (ushort_t*)(ws + (size_t)13 * (1u << 20)); // 8 MB
  ushort_t* VT   = (ushort_t*)(ws + (size_t)21 * (1u << 20)); // 4 MB
  float*    O    = (float*)(ws + (size_t)25 * (1u << 20));    // 8 MB
  double*   pch  = (double*)(ws + (size_t)33 * (1u << 20));   // 640 KB
  float*    coef = (float*)(ws + (size_t)34 * (1u << 20));    // 2.5 KB
  float*    out  = (float*)d_out;

  k_conv1  <<<256, 256, 0, stream>>>(x, q1_w, q1_b, kv1_w, kv1_b, y_q, y_kv, pch);
  k_stats  <<<1,   256, 0, stream>>>(pch, q_gn_g, q_gn_b, kv_gn_g, kv_gn_b, kvn_g, kvn_b, coef);
  k_buildq <<<256, 256, 0, stream>>>(y_q, coef, q2_w, q2_b, Q);
  k_buildkv<<<640, 256, 0, stream>>>(y_kv, coef, kvup_w, kvup_b, K, VT);
  k_attn   <<<512, 256, 0, stream>>>(Q, K, VT, O);
  k_outconv<<<512, 256, 0, stream>>>(O, out_w, out_b, x, out);
}

// Round 3
// 315.162 us; speedup vs baseline: 2.4561x; 1.3273x over previous
//
#include <hip/hip_runtime.h>

typedef unsigned short ushort_t;
typedef unsigned int uint_t;
typedef __attribute__((ext_vector_type(8))) short s16x8;
typedef __attribute__((ext_vector_type(4))) float f32x4;

#define S_TOT 4096
#define QSCALE 0.08838834764831845f       // 1/sqrt(128)
#define LOG2E 1.4426950408889634f
#define QSL (QSCALE * LOG2E)              // baked into Q -> attn uses exp2
#define L2_10000_D16 0.8304820237218406f  // log2(10000)/16

__device__ __forceinline__ ushort_t f2b(float f) {
  uint_t u = __float_as_uint(f);
  uint_t r = (u + 0x7FFFu + ((u >> 16) & 1u)) >> 16;
  return (ushort_t)r;
}

template <int N8>
__device__ __forceinline__ void store_rowN(ushort_t* dst, const float* a) {
#pragma unroll
  for (int i = 0; i < N8; i++) {
    union { ushort_t u[8]; s16x8 v; } pk;
#pragma unroll
    for (int j = 0; j < 8; j++) pk.u[j] = f2b(a[i * 8 + j]);
    *(s16x8*)(dst + i * 8) = pk.v;
  }
}

// rope over NP pairs starting at global pair index pb; in-place on v[2*NP]
template <int NP>
__device__ __forceinline__ void ropeN(float* v, int pb, int hi, int wi, float scale) {
#pragma unroll
  for (int kk = 0; kk < NP; kk++) {
    int p = pb + kk;
    int j = p >> 1;
    float inv = exp2f(-(float)j * L2_10000_D16);
    float ang = ((p & 1) ? (float)wi : (float)hi) * inv;
    float sn = sinf(ang), cs = cosf(ang);
    float x0 = v[2 * kk], x1 = v[2 * kk + 1];
    v[2 * kk]     = (x0 * sn - x1 * cs) * scale;
    v[2 * kk + 1] = (x0 * cs + x1 * sn) * scale;
  }
}

__device__ __forceinline__ void gload16(const void* g, void* l) {
  __builtin_amdgcn_global_load_lds(
      (const __attribute__((address_space(1))) unsigned int*)g,
      (__attribute__((address_space(3))) unsigned int*)l, 16, 0, 0);
}

__device__ __forceinline__ float xor16f(float v) {
  return __int_as_float(__builtin_amdgcn_ds_swizzle(__float_as_int(v), 0x401F));
}

// ---------------------------------------------------------------------------
// K1: y_q = q1_w@x + b (B,32,S); y_kv = kv1_w@x + b (B,128,S)
// + per-channel per-block partial (sum,sumsq) -> pch[b][blk(256)][160][2]
// grid B*256 (16 s per block), block 256: si=t&15, g=t>>4 (16 groups x 10 ch)
__global__ __launch_bounds__(256) void k_conv1(
    const float* __restrict__ x, const float* __restrict__ q1_w, const float* __restrict__ q1_b,
    const float* __restrict__ kv1_w, const float* __restrict__ kv1_b,
    float* __restrict__ y_q, float* __restrict__ y_kv, double* __restrict__ pch) {
  const int b = blockIdx.x >> 8, blk = blockIdx.x & 255, st = blk * 16;
  const int t = threadIdx.x, si = t & 15, g = t >> 4;
  __shared__ float xs[128][16];
#pragma unroll
  for (int i = 0; i < 8; i++) {
    int c = g + 16 * i;
    xs[c][si] = x[(size_t)(b * 128 + c) * S_TOT + st + si];
  }
  __syncthreads();
  float acc[10];
#pragma unroll
  for (int i = 0; i < 10; i++) {
    int oc = g * 10 + i;
    acc[i] = (oc < 32) ? q1_b[oc] : kv1_b[oc - 32];
  }
  const float4* q1w4 = (const float4*)q1_w;
  const float4* kv1w4 = (const float4*)kv1_w;
  for (int c4 = 0; c4 < 32; c4++) {
    float x0 = xs[c4 * 4 + 0][si], x1 = xs[c4 * 4 + 1][si];
    float x2 = xs[c4 * 4 + 2][si], x3 = xs[c4 * 4 + 3][si];
#pragma unroll
    for (int i = 0; i < 10; i++) {
      int oc = g * 10 + i;
      float4 wv = (oc < 32) ? q1w4[oc * 32 + c4] : kv1w4[(oc - 32) * 32 + c4];
      acc[i] += wv.x * x0 + wv.y * x1 + wv.z * x2 + wv.w * x3;
    }
  }
  double* pbase = pch + (size_t)(b * 256 + blk) * 320;
#pragma unroll
  for (int i = 0; i < 10; i++) {
    int oc = g * 10 + i;
    float a = acc[i];
    if (oc < 32) y_q[(size_t)(b * 32 + oc) * S_TOT + st + si] = a;
    else         y_kv[(size_t)(b * 128 + oc - 32) * S_TOT + st + si] = a;
    double s = a, q = (double)a * a;
#pragma unroll
    for (int o = 1; o < 16; o <<= 1) { s += __shfl_xor(s, o, 16); q += __shfl_xor(q, o, 16); }
    if (si == 0) { pbase[oc * 2] = s; pbase[oc * 2 + 1] = q; }
  }
}

// ---------------------------------------------------------------------------
// K2: reduce partials, compose all group-norms into per-channel affine coefs.
// coef per b (320 floats): [qA|qB|krA|krB|kvnA|kvnB]
__global__ __launch_bounds__(256) void k_stats(
    const double* __restrict__ pch,
    const float* __restrict__ qg, const float* __restrict__ qb,
    const float* __restrict__ kvg, const float* __restrict__ kvb,
    const float* __restrict__ kng, const float* __restrict__ knb,
    float* __restrict__ coef) {
  __shared__ double Sh[2][160], Qh[2][160];
  for (int idx = threadIdx.x; idx < 320; idx += 256) {
    int b = idx / 160, c = idx % 160;
    double s = 0, q = 0;
    for (int blkk = 0; blkk < 256; blkk++) {
      const double* p = pch + ((size_t)(b * 256 + blkk) * 160 + c) * 2;
      s += p[0]; q += p[1];
    }
    Sh[b][c] = s; Qh[b][c] = q;
  }
  __syncthreads();
  if (threadIdx.x < 2) {
    int b = threadIdx.x;
    float* cf = coef + b * 320;
    const double NS = 4096.0;
    double muq = 0, m2q = 0;
    for (int c = 0; c < 32; c++) { muq += Sh[b][c]; m2q += Qh[b][c]; }
    muq /= (32.0 * NS); m2q /= (32.0 * NS);
    double rstdq = 1.0 / sqrt(m2q - muq * muq + 1e-5);
    for (int c = 0; c < 32; c++) {
      double A = rstdq * (double)qg[c];
      cf[c] = (float)A; cf[32 + c] = (float)((double)qb[c] - muq * A);
    }
    double mukv = 0, m2kv = 0;
    for (int c = 0; c < 128; c++) { mukv += Sh[b][32 + c]; m2kv += Qh[b][32 + c]; }
    mukv /= (128.0 * NS); m2kv /= (128.0 * NS);
    double rstdkv = 1.0 / sqrt(m2kv - mukv * mukv + 1e-5);
    for (int c = 0; c < 64; c++) {
      double A = rstdkv * (double)kvg[c];
      cf[64 + c] = (float)A; cf[128 + c] = (float)((double)kvb[c] - mukv * A);
    }
    double mu2 = 0, m22 = 0;
    for (int c2 = 0; c2 < 64; c2++) {
      int c = 64 + c2;
      double a = rstdkv * (double)kvg[c], bb = (double)kvb[c] - mukv * a;
      double Ec = Sh[b][32 + c] / NS, M2c = Qh[b][32 + c] / NS;
      mu2 += a * Ec + bb;
      m22 += a * a * M2c + 2.0 * a * bb * Ec + bb * bb;
    }
    mu2 /= 64.0; m22 /= 64.0;
    double rstd2 = 1.0 / sqrt(m22 - mu2 * mu2 + 1e-5);
    for (int c2 = 0; c2 < 64; c2++) {
      int c = 64 + c2;
      double a = rstdkv * (double)kvg[c], bb = (double)kvb[c] - mukv * a;
      cf[192 + c2] = (float)(a * rstd2 * (double)kng[c2]);
      cf[256 + c2] = (float)((bb - mu2) * rstd2 * (double)kng[c2] + (double)knb[c2]);
    }
  }
}

// ---------------------------------------------------------------------------
// K3: Q build. grid B*64*4 (chunk = 32-d slice), block 256, wave = head.
// Q scaled by QSCALE*log2e (attn works in exp2 domain).
__global__ __launch_bounds__(256) void k_buildq(
    const float* __restrict__ y_q, const float* __restrict__ coef,
    const float* __restrict__ q2_w, const float* __restrict__ q2_b,
    ushort_t* __restrict__ Q) {
  int id = blockIdx.x;
  const int chunk = id & 3; id >>= 2;
  const int b = id >> 6, blk = id & 63, st = blk * 64;
  const int t = threadIdx.x, si = t & 63, h = t >> 6;
  const float* cf = coef + b * 320;
  __shared__ float qn[32][64];
#pragma unroll
  for (int i = 0; i < 8; i++) {
    int c = h + 4 * i;
    float v = y_q[(size_t)(b * 32 + c) * S_TOT + st + si];
    qn[c][si] = v * cf[c] + cf[32 + c];
  }
  __syncthreads();
  float qv[32];
#pragma unroll
  for (int c = 0; c < 32; c++) qv[c] = qn[c][si];
  const int sp = st + si, hi = sp >> 6, wi = sp & 63;
  const int dbase = chunk * 32;
  ushort_t* qrow = Q + ((size_t)(b * 4 + h) * S_TOT + sp) * 128;
  const float4* w4 = (const float4*)q2_w;
  float acc[32];
#pragma unroll
  for (int d = 0; d < 32; d++) {
    int oc = h * 128 + dbase + d;
    float a = q2_b[oc];
#pragma unroll
    for (int c4 = 0; c4 < 8; c4++) {
      float4 wv = w4[oc * 8 + c4];
      a += wv.x * qv[c4 * 4] + wv.y * qv[c4 * 4 + 1] + wv.z * qv[c4 * 4 + 2] + wv.w * qv[c4 * 4 + 3];
    }
    acc[d] = a;
  }
  if (dbase < 64) {
#pragma unroll
    for (int d = 0; d < 32; d++) acc[d] *= QSL;
  } else {
    ropeN<16>(acc, (dbase - 64) >> 1, hi, wi, QSL);
  }
  store_rowN<4>(qrow + dbase, acc);
}

// ---------------------------------------------------------------------------
// K4: KV build. grid B*64*9. chunks 0-3: k_nope 16-d slices; 4-7: v 16-d
// slices; 8: k_rope. block 256, wave = head.
__global__ __launch_bounds__(256) void k_buildkv(
    const float* __restrict__ y_kv, const float* __restrict__ coef,
    const float* __restrict__ kvup_w, const float* __restrict__ kvup_b,
    ushort_t* __restrict__ K, ushort_t* __restrict__ VT) {
  int id = blockIdx.x;
  const int chunk = id % 9; id /= 9;
  const int b = id >> 6, blk = id & 63, st = blk * 64;
  const int t = threadIdx.x, si = t & 63, h = t >> 6;
  const float* cf = coef + b * 320;
  const int sp = st + si;
  ushort_t* krow = K + ((size_t)(b * 4 + h) * S_TOT + sp) * 128;
  __shared__ float tile[64][64];
  if (chunk == 8) {
#pragma unroll
    for (int i = 0; i < 16; i++) {
      int c = h + 4 * i;
      float v = y_kv[(size_t)(b * 128 + c) * S_TOT + st + si];
      tile[c][si] = v * cf[64 + c] + cf[128 + c];
    }
    __syncthreads();
    float kr[64];
#pragma unroll
    for (int c = 0; c < 64; c++) kr[c] = tile[c][si];
    ropeN<32>(kr, 0, sp >> 6, sp & 63, 1.0f);
    store_rowN<8>(krow + 64, kr);
    return;
  }
#pragma unroll
  for (int i = 0; i < 16; i++) {
    int c = h + 4 * i;
    float v = y_kv[(size_t)(b * 128 + 64 + c) * S_TOT + st + si];
    tile[c][si] = v * cf[192 + c] + cf[256 + c];
  }
  __syncthreads();
  float kvv[64];
#pragma unroll
  for (int c = 0; c < 64; c++) kvv[c] = tile[c][si];
  const int vsel = chunk >> 2, dq = chunk & 3;
  const float4* w4 = (const float4*)kvup_w;
  float acc[16];
#pragma unroll
  for (int d = 0; d < 16; d++) {
    int oc = h * 128 + vsel * 64 + dq * 16 + d;
    float a = kvup_b[oc];
#pragma unroll
    for (int c4 = 0; c4 < 16; c4++) {
      float4 wv = w4[oc * 16 + c4];
      a += wv.x * kvv[c4 * 4] + wv.y * kvv[c4 * 4 + 1] + wv.z * kvv[c4 * 4 + 2] + wv.w * kvv[c4 * 4 + 3];
    }
    acc[d] = a;
  }
  if (vsel == 0) {
    store_rowN<2>(krow + dq * 16, acc);
  } else {
    ushort_t* vbase = VT + (size_t)(b * 4 + h) * 64 * S_TOT + sp;
#pragma unroll
    for (int d = 0; d < 16; d++) vbase[(size_t)(dq * 16 + d) * S_TOT] = f2b(acc[d]);
  }
}

// ---------------------------------------------------------------------------
// K5: flash attention, swapped-QK^T in-register softmax (exp2 domain),
// KV tile 64, LDS-staged K+V double-buffered (global_load_lds, m173 swizzle),
// defer-max rescale, XCD-bijective block swizzle.
// grid 512 = 8 bh x 64 qblk, block 256 = 4 waves x 16 q-rows.
__global__ __launch_bounds__(256) void k_attn(
    const ushort_t* __restrict__ Q, const ushort_t* __restrict__ K,
    const ushort_t* __restrict__ VT, float* __restrict__ O) {
  int bid = blockIdx.x;
  bid = (bid & 7) * 64 + (bid >> 3);       // XCD swizzle: one bh per XCD
  const int bh = bid >> 6, qblk = bid & 63;
  const int tid = threadIdx.x;
  const int wid = tid >> 6, lane = tid & 63;
  const int l15 = lane & 15, lg = lane >> 4;
  const int qbase = qblk * 64 + wid * 16;
  const ushort_t* Qp = Q + (size_t)bh * S_TOT * 128;
  const ushort_t* Kp = K + (size_t)bh * S_TOT * 128;
  const ushort_t* Vp = VT + (size_t)bh * 64 * S_TOT;

  __shared__ __align__(16) ushort_t K_lds[2][64][128];  // 2 x 16 KB
  __shared__ __align__(16) ushort_t V_lds[2][64][64];   // 2 x 8 KB
  __shared__ __align__(16) ushort_t P_lds[4][16][64];   // 8 KB

  s16x8 qa[4];
#pragma unroll
  for (int kk = 0; kk < 4; kk++)
    qa[kk] = *(const s16x8*)(Qp + (size_t)(qbase + l15) * 128 + kk * 32 + lg * 8);

  f32x4 o_acc[4];
#pragma unroll
  for (int n = 0; n < 4; n++) o_acc[n] = (f32x4){0.f, 0.f, 0.f, 0.f};
  float m_s = -1e30f, l_s = 0.f;   // per-lane state for q = qbase + l15

  const int krow_l = wid * 4 + (lane >> 4);
  const int kcol_l = (lane & 15) * 16;
  const int vrow_l = wid * 8 + (lane >> 3);
  const int vcol_l = (lane & 7) * 16;

#define STAGE(kvb, bufi)                                                          \
  {                                                                               \
    _Pragma("unroll")                                                             \
    for (int i = 0; i < 4; i++) {                                                 \
      int row = i * 16 + krow_l;                                                  \
      int colb = kcol_l ^ ((row & 7) << 4);                                       \
      gload16((const char*)(Kp + (size_t)((kvb) + row) * 128) + colb,             \
              (void*)&K_lds[bufi][i * 16 + wid * 4][0]);                          \
    }                                                                             \
    _Pragma("unroll")                                                             \
    for (int i = 0; i < 2; i++) {                                                 \
      int vd = i * 32 + vrow_l;                                                   \
      int colb = vcol_l ^ ((vd & 7) << 4);                                        \
      gload16((const char*)(Vp + (size_t)vd * S_TOT + (kvb)) + colb,              \
              (void*)&V_lds[bufi][i * 32 + wid * 8][0]);                          \
    }                                                                             \
  }

  STAGE(0, 0);
  __syncthreads();

  const int swz = (l15 & 7) << 4;
  char* pbase = (char*)&P_lds[wid][l15][0];
#pragma unroll 1
  for (int t = 0; t < 64; t++) {
    const int buf = t & 1;
    if (t < 63) STAGE((t + 1) * 64, buf ^ 1);
    // swapped QK^T: sc[cb][r] = S^T[kv = cb*16+lg*4+r][q = l15]
    f32x4 sc[4];
#pragma unroll
    for (int cb = 0; cb < 4; cb++) sc[cb] = (f32x4){0.f, 0.f, 0.f, 0.f};
#pragma unroll
    for (int kk = 0; kk < 4; kk++) {
#pragma unroll
      for (int cb = 0; cb < 4; cb++) {
        const int row = cb * 16 + l15;
        const int off = (kk * 64 + lg * 16) ^ swz;
        s16x8 kf = *(const s16x8*)((const char*)&K_lds[buf][row][0] + off);
        sc[cb] = __builtin_amdgcn_mfma_f32_16x16x32_bf16(kf, qa[kk], sc[cb], 0, 0, 0);
      }
    }
    // in-register row max (16 vals) + 2 cross-lane
    float pmax;
    {
      float a0 = fmaxf(fmaxf(sc[0][0], sc[0][1]), fmaxf(sc[0][2], sc[0][3]));
      float a1 = fmaxf(fmaxf(sc[1][0], sc[1][1]), fmaxf(sc[1][2], sc[1][3]));
      float a2 = fmaxf(fmaxf(sc[2][0], sc[2][1]), fmaxf(sc[2][2], sc[2][3]));
      float a3 = fmaxf(fmaxf(sc[3][0], sc[3][1]), fmaxf(sc[3][2], sc[3][3]));
      pmax = fmaxf(fmaxf(a0, a1), fmaxf(a2, a3));
    }
    pmax = fmaxf(pmax, xor16f(pmax));
    pmax = fmaxf(pmax, __shfl_xor(pmax, 32, 64));
    if (__any(pmax - m_s > 11.5f)) {   // defer-max: rescale only when needed
      float mn = fmaxf(m_s, pmax);
      float alpha = exp2f(m_s - mn);
      m_s = mn;
      l_s *= alpha;
      float ar[4];
#pragma unroll
      for (int r = 0; r < 4; r++) ar[r] = __shfl(alpha, lg * 20 + r, 64);
#pragma unroll
      for (int n = 0; n < 4; n++)
#pragma unroll
        for (int r = 0; r < 4; r++) o_acc[n][r] *= ar[r];
    }
    float rs = 0.f;
#pragma unroll
    for (int cb = 0; cb < 4; cb++)
#pragma unroll
      for (int r = 0; r < 4; r++) {
        float p = exp2f(sc[cb][r] - m_s);
        sc[cb][r] = p; rs += p;
      }
    rs += xor16f(rs);
    rs += __shfl_xor(rs, 32, 64);
    l_s += rs;
    // P -> LDS (packed u32, swizzled): row = l15 (q), col = kv
#pragma unroll
    for (int cb = 0; cb < 4; cb++) {
      uint_t lo = (uint_t)f2b(sc[cb][0]) | ((uint_t)f2b(sc[cb][1]) << 16);
      uint_t hi = (uint_t)f2b(sc[cb][2]) | ((uint_t)f2b(sc[cb][3]) << 16);
      *(uint_t*)(pbase + ((cb * 32 + lg * 8) ^ swz)) = lo;
      *(uint_t*)(pbase + ((cb * 32 + lg * 8 + 4) ^ swz)) = hi;
    }
    asm volatile("s_waitcnt lgkmcnt(0)" ::: "memory");
    __builtin_amdgcn_sched_barrier(0);
#pragma unroll
    for (int ks = 0; ks < 2; ks++) {
      const int off = (ks * 64 + lg * 16) ^ swz;
      s16x8 pa = *(const s16x8*)(pbase + off);
#pragma unroll
      for (int n = 0; n < 4; n++) {
        s16x8 vb = *(const s16x8*)((const char*)&V_lds[buf][n * 16 + l15][0] + off);
        o_acc[n] = __builtin_amdgcn_mfma_f32_16x16x32_bf16(pa, vb, o_acc[n], 0, 0, 0);
      }
    }
    __syncthreads();
  }
#undef STAGE
  float linv = 1.f / l_s;
  float invr[4];
#pragma unroll
  for (int r = 0; r < 4; r++) invr[r] = __shfl(linv, lg * 20 + r, 64);
#pragma unroll
  for (int n = 0; n < 4; n++)
#pragma unroll
    for (int r = 0; r < 4; r++)
      O[((size_t)bh * S_TOT + qbase + lg * 4 + r) * 64 + n * 16 + l15] = o_acc[n][r] * invr[r];
}

// ---------------------------------------------------------------------------
// K6: out conv + residual. grid B*128*4 (32-ch chunks), block 256.
__global__ __launch_bounds__(256) void k_outconv(
    const float* __restrict__ O, const float* __restrict__ out_w, const float* __restrict__ out_b,
    const float* __restrict__ x, float* __restrict__ out) {
  int id = blockIdx.x;
  const int chunk = id & 3; id >>= 2;
  const int b = id >> 7, blk = id & 127, st = blk * 32;
  const int t = threadIdx.x;
  __shared__ float o_lds[256][33];
  {
    int vd = t & 63, r0 = t >> 6;
#pragma unroll
    for (int i = 0; i < 32; i++) {
      int hs = r0 + 4 * i;
      int h = hs >> 5, ss2 = hs & 31;
      o_lds[h * 64 + vd][ss2] = O[((size_t)(b * 4 + h) * S_TOT + st + ss2) * 64 + vd];
    }
  }
  __syncthreads();
  const int si = t & 31, g = t >> 5;
  const float4* w4 = (const float4*)out_w;
#pragma unroll
  for (int i = 0; i < 4; i++) {
    int c = chunk * 32 + g + 8 * i;
    float a = out_b[c];
#pragma unroll 8
    for (int hv4 = 0; hv4 < 64; hv4++) {
      float4 wv = w4[c * 64 + hv4];
      a += wv.x * o_lds[hv4 * 4 + 0][si] + wv.y * o_lds[hv4 * 4 + 1][si]
         + wv.z * o_lds[hv4 * 4 + 2][si] + wv.w * o_lds[hv4 * 4 + 3][si];
    }
    size_t idx = (size_t)(b * 128 + c) * S_TOT + st + si;
    out[idx] = a + x[idx];
  }
}

// ---------------------------------------------------------------------------
extern "C" void kernel_launch(void* const* d_in, const int* in_sizes, int n_in,
                              void* d_out, int out_size, void* d_ws, size_t ws_size,
                              hipStream_t stream) {
  const float* x      = (const float*)d_in[0];
  const float* q1_w   = (const float*)d_in[1];
  const float* q1_b   = (const float*)d_in[2];
  const float* q_gn_g = (const float*)d_in[3];
  const float* q_gn_b = (const float*)d_in[4];
  const float* q2_w   = (const float*)d_in[5];
  const float* q2_b   = (const float*)d_in[6];
  const float* kv1_w  = (const float*)d_in[7];
  const float* kv1_b  = (const float*)d_in[8];
  const float* kv_gn_g= (const float*)d_in[9];
  const float* kv_gn_b= (const float*)d_in[10];
  const float* kvn_g  = (const float*)d_in[11];
  const float* kvn_b  = (const float*)d_in[12];
  const float* kvup_w = (const float*)d_in[13];
  const float* kvup_b = (const float*)d_in[14];
  const float* out_w  = (const float*)d_in[15];
  const float* out_b  = (const float*)d_in[16];

  char* ws = (char*)d_ws;
  float*    y_q  = (float*)(ws);                              // 1 MB
  float*    y_kv = (float*)(ws + (size_t)1  * (1u << 20));    // 4 MB
  ushort_t* Q    = (ushort_t*)(ws + (size_t)5  * (1u << 20)); // 8 MB
  ushort_t* K    = (ushort_t*)(ws + (size_t)13 * (1u << 20)); // 8 MB
  ushort_t* VT   = (ushort_t*)(ws + (size_t)21 * (1u << 20)); // 4 MB
  float*    O    = (float*)(ws + (size_t)25 * (1u << 20));    // 8 MB
  double*   pch  = (double*)(ws + (size_t)33 * (1u << 20));   // 1.31 MB
  float*    coef = (float*)(ws + (size_t)35 * (1u << 20));    // 2.5 KB
  float*    out  = (float*)d_out;

  k_conv1  <<<512,  256, 0, stream>>>(x, q1_w, q1_b, kv1_w, kv1_b, y_q, y_kv, pch);
  k_stats  <<<1,    256, 0, stream>>>(pch, q_gn_g, q_gn_b, kv_gn_g, kv_gn_b, kvn_g, kvn_b, coef);
  k_buildq <<<512,  256, 0, stream>>>(y_q, coef, q2_w, q2_b, Q);
  k_buildkv<<<1152, 256, 0, stream>>>(y_kv, coef, kvup_w, kvup_b, K, VT);
  k_attn   <<<512,  256, 0, stream>>>(Q, K, VT, O);
  k_outconv<<<1024, 256, 0, stream>>>(O, out_w, out_b, x, out);
}

// Round 4
// 299.692 us; speedup vs baseline: 2.5829x; 1.0516x over previous
//
#include <hip/hip_runtime.h>

typedef unsigned short ushort_t;
typedef unsigned int uint_t;
typedef __attribute__((ext_vector_type(8))) short s16x8;
typedef __attribute__((ext_vector_type(4))) float f32x4;

#define S_TOT 4096
#define QSCALE 0.08838834764831845f       // 1/sqrt(128)
#define LOG2E 1.4426950408889634f
#define QSL (QSCALE * LOG2E)              // baked into Q -> attn uses exp2
#define L2_10000_D16 0.8304820237218406f  // log2(10000)/16

__device__ __forceinline__ ushort_t f2b(float f) {
  uint_t u = __float_as_uint(f);
  uint_t r = (u + 0x7FFFu + ((u >> 16) & 1u)) >> 16;
  return (ushort_t)r;
}

__device__ __forceinline__ uint_t cvt_pk_bf16(float lo, float hi) {
  uint_t r;
  asm("v_cvt_pk_bf16_f32 %0, %1, %2" : "=v"(r) : "v"(lo), "v"(hi));
  return r;
}

template <int N8>
__device__ __forceinline__ void store_rowN(ushort_t* dst, const float* a) {
#pragma unroll
  for (int i = 0; i < N8; i++) {
    union { ushort_t u[8]; s16x8 v; } pk;
#pragma unroll
    for (int j = 0; j < 8; j++) pk.u[j] = f2b(a[i * 8 + j]);
    *(s16x8*)(dst + i * 8) = pk.v;
  }
}

// rope over NP pairs starting at global pair index pb; in-place on v[2*NP]
template <int NP>
__device__ __forceinline__ void ropeN(float* v, int pb, int hi, int wi, float scale) {
#pragma unroll
  for (int kk = 0; kk < NP; kk++) {
    int p = pb + kk;
    int j = p >> 1;
    float inv = exp2f(-(float)j * L2_10000_D16);
    float ang = ((p & 1) ? (float)wi : (float)hi) * inv;
    float sn = sinf(ang), cs = cosf(ang);
    float x0 = v[2 * kk], x1 = v[2 * kk + 1];
    v[2 * kk]     = (x0 * sn - x1 * cs) * scale;
    v[2 * kk + 1] = (x0 * cs + x1 * sn) * scale;
  }
}

__device__ __forceinline__ void gload16(const void* g, void* l) {
  __builtin_amdgcn_global_load_lds(
      (const __attribute__((address_space(1))) unsigned int*)g,
      (__attribute__((address_space(3))) unsigned int*)l, 16, 0, 0);
}

__device__ __forceinline__ float xor16f(float v) {
  return __int_as_float(__builtin_amdgcn_ds_swizzle(__float_as_int(v), 0x401F));
}

// ---------------------------------------------------------------------------
// K1: y_q = q1_w@x + b (B,32,S); y_kv = kv1_w@x + b (B,128,S)
// + per-channel per-block partial (sum,sumsq) -> pch[b][blk(256)][160][2]
__global__ __launch_bounds__(256) void k_conv1(
    const float* __restrict__ x, const float* __restrict__ q1_w, const float* __restrict__ q1_b,
    const float* __restrict__ kv1_w, const float* __restrict__ kv1_b,
    float* __restrict__ y_q, float* __restrict__ y_kv, double* __restrict__ pch) {
  const int b = blockIdx.x >> 8, blk = blockIdx.x & 255, st = blk * 16;
  const int t = threadIdx.x, si = t & 15, g = t >> 4;
  __shared__ float xs[128][16];
#pragma unroll
  for (int i = 0; i < 8; i++) {
    int c = g + 16 * i;
    xs[c][si] = x[(size_t)(b * 128 + c) * S_TOT + st + si];
  }
  __syncthreads();
  float acc[10];
#pragma unroll
  for (int i = 0; i < 10; i++) {
    int oc = g * 10 + i;
    acc[i] = (oc < 32) ? q1_b[oc] : kv1_b[oc - 32];
  }
  const float4* q1w4 = (const float4*)q1_w;
  const float4* kv1w4 = (const float4*)kv1_w;
  for (int c4 = 0; c4 < 32; c4++) {
    float x0 = xs[c4 * 4 + 0][si], x1 = xs[c4 * 4 + 1][si];
    float x2 = xs[c4 * 4 + 2][si], x3 = xs[c4 * 4 + 3][si];
#pragma unroll
    for (int i = 0; i < 10; i++) {
      int oc = g * 10 + i;
      float4 wv = (oc < 32) ? q1w4[oc * 32 + c4] : kv1w4[(oc - 32) * 32 + c4];
      acc[i] += wv.x * x0 + wv.y * x1 + wv.z * x2 + wv.w * x3;
    }
  }
  double* pbase = pch + (size_t)(b * 256 + blk) * 320;
#pragma unroll
  for (int i = 0; i < 10; i++) {
    int oc = g * 10 + i;
    float a = acc[i];
    if (oc < 32) y_q[(size_t)(b * 32 + oc) * S_TOT + st + si] = a;
    else         y_kv[(size_t)(b * 128 + oc - 32) * S_TOT + st + si] = a;
    double s = a, q = (double)a * a;
#pragma unroll
    for (int o = 1; o < 16; o <<= 1) { s += __shfl_xor(s, o, 16); q += __shfl_xor(q, o, 16); }
    if (si == 0) { pbase[oc * 2] = s; pbase[oc * 2 + 1] = q; }
  }
}

// ---------------------------------------------------------------------------
// K2: reduce partials (sliced, pipelined), compose group-norms into affine coefs.
__global__ __launch_bounds__(1024) void k_stats(
    const double* __restrict__ pch,
    const float* __restrict__ qg, const float* __restrict__ qb,
    const float* __restrict__ kvg, const float* __restrict__ kvb,
    const float* __restrict__ kng, const float* __restrict__ knb,
    float* __restrict__ coef) {
  __shared__ double Sh[2][160], Qh[2][160];
  __shared__ double part[320][4][2];
  for (int work = threadIdx.x; work < 1280; work += 1024) {
    int pair = work >> 2, slice = work & 3;
    int b = pair / 160, c = pair % 160;
    double s = 0, q = 0;
    const double* p = pch + (size_t)(b * 256 + slice * 64) * 320 + c * 2;
#pragma unroll 8
    for (int k = 0; k < 64; k++) { s += p[(size_t)k * 320]; q += p[(size_t)k * 320 + 1]; }
    part[pair][slice][0] = s; part[pair][slice][1] = q;
  }
  __syncthreads();
  if (threadIdx.x < 320) {
    int pair = threadIdx.x, b = pair / 160, c = pair % 160;
    Sh[b][c] = part[pair][0][0] + part[pair][1][0] + part[pair][2][0] + part[pair][3][0];
    Qh[b][c] = part[pair][0][1] + part[pair][1][1] + part[pair][2][1] + part[pair][3][1];
  }
  __syncthreads();
  if (threadIdx.x < 2) {
    int b = threadIdx.x;
    float* cf = coef + b * 320;
    const double NS = 4096.0;
    double muq = 0, m2q = 0;
    for (int c = 0; c < 32; c++) { muq += Sh[b][c]; m2q += Qh[b][c]; }
    muq /= (32.0 * NS); m2q /= (32.0 * NS);
    double rstdq = 1.0 / sqrt(m2q - muq * muq + 1e-5);
    for (int c = 0; c < 32; c++) {
      double A = rstdq * (double)qg[c];
      cf[c] = (float)A; cf[32 + c] = (float)((double)qb[c] - muq * A);
    }
    double mukv = 0, m2kv = 0;
    for (int c = 0; c < 128; c++) { mukv += Sh[b][32 + c]; m2kv += Qh[b][32 + c]; }
    mukv /= (128.0 * NS); m2kv /= (128.0 * NS);
    double rstdkv = 1.0 / sqrt(m2kv - mukv * mukv + 1e-5);
    for (int c = 0; c < 64; c++) {
      double A = rstdkv * (double)kvg[c];
      cf[64 + c] = (float)A; cf[128 + c] = (float)((double)kvb[c] - mukv * A);
    }
    double mu2 = 0, m22 = 0;
    for (int c2 = 0; c2 < 64; c2++) {
      int c = 64 + c2;
      double a = rstdkv * (double)kvg[c], bb = (double)kvb[c] - mukv * a;
      double Ec = Sh[b][32 + c] / NS, M2c = Qh[b][32 + c] / NS;
      mu2 += a * Ec + bb;
      m22 += a * a * M2c + 2.0 * a * bb * Ec + bb * bb;
    }
    mu2 /= 64.0; m22 /= 64.0;
    double rstd2 = 1.0 / sqrt(m22 - mu2 * mu2 + 1e-5);
    for (int c2 = 0; c2 < 64; c2++) {
      int c = 64 + c2;
      double a = rstdkv * (double)kvg[c], bb = (double)kvb[c] - mukv * a;
      cf[192 + c2] = (float)(a * rstd2 * (double)kng[c2]);
      cf[256 + c2] = (float)((bb - mu2) * rstd2 * (double)kng[c2] + (double)knb[c2]);
    }
  }
}

// ---------------------------------------------------------------------------
// K3: Q build. grid B*64*4 (chunk = 32-d slice), block 256, wave = head.
__global__ __launch_bounds__(256) void k_buildq(
    const float* __restrict__ y_q, const float* __restrict__ coef,
    const float* __restrict__ q2_w, const float* __restrict__ q2_b,
    ushort_t* __restrict__ Q) {
  int id = blockIdx.x;
  const int chunk = id & 3; id >>= 2;
  const int b = id >> 6, blk = id & 63, st = blk * 64;
  const int t = threadIdx.x, si = t & 63, h = t >> 6;
  const float* cf = coef + b * 320;
  __shared__ float qn[32][64];
#pragma unroll
  for (int i = 0; i < 8; i++) {
    int c = h + 4 * i;
    float v = y_q[(size_t)(b * 32 + c) * S_TOT + st + si];
    qn[c][si] = v * cf[c] + cf[32 + c];
  }
  __syncthreads();
  float qv[32];
#pragma unroll
  for (int c = 0; c < 32; c++) qv[c] = qn[c][si];
  const int sp = st + si, hi = sp >> 6, wi = sp & 63;
  const int dbase = chunk * 32;
  ushort_t* qrow = Q + ((size_t)(b * 4 + h) * S_TOT + sp) * 128;
  const float4* w4 = (const float4*)q2_w;
  float acc[32];
#pragma unroll
  for (int d = 0; d < 32; d++) {
    int oc = h * 128 + dbase + d;
    float a = q2_b[oc];
#pragma unroll
    for (int c4 = 0; c4 < 8; c4++) {
      float4 wv = w4[oc * 8 + c4];
      a += wv.x * qv[c4 * 4] + wv.y * qv[c4 * 4 + 1] + wv.z * qv[c4 * 4 + 2] + wv.w * qv[c4 * 4 + 3];
    }
    acc[d] = a;
  }
  if (dbase < 64) {
#pragma unroll
    for (int d = 0; d < 32; d++) acc[d] *= QSL;
  } else {
    ropeN<16>(acc, (dbase - 64) >> 1, hi, wi, QSL);
  }
  store_rowN<4>(qrow + dbase, acc);
}

// ---------------------------------------------------------------------------
// K4: KV build. grid B*64*9. chunks 0-3: k_nope; 4-7: v; 8: k_rope.
__global__ __launch_bounds__(256) void k_buildkv(
    const float* __restrict__ y_kv, const float* __restrict__ coef,
    const float* __restrict__ kvup_w, const float* __restrict__ kvup_b,
    ushort_t* __restrict__ K, ushort_t* __restrict__ VT) {
  int id = blockIdx.x;
  const int chunk = id % 9; id /= 9;
  const int b = id >> 6, blk = id & 63, st = blk * 64;
  const int t = threadIdx.x, si = t & 63, h = t >> 6;
  const float* cf = coef + b * 320;
  const int sp = st + si;
  ushort_t* krow = K + ((size_t)(b * 4 + h) * S_TOT + sp) * 128;
  __shared__ float tile[64][64];
  if (chunk == 8) {
#pragma unroll
    for (int i = 0; i < 16; i++) {
      int c = h + 4 * i;
      float v = y_kv[(size_t)(b * 128 + c) * S_TOT + st + si];
      tile[c][si] = v * cf[64 + c] + cf[128 + c];
    }
    __syncthreads();
    float kr[64];
#pragma unroll
    for (int c = 0; c < 64; c++) kr[c] = tile[c][si];
    ropeN<32>(kr, 0, sp >> 6, sp & 63, 1.0f);
    store_rowN<8>(krow + 64, kr);
    return;
  }
#pragma unroll
  for (int i = 0; i < 16; i++) {
    int c = h + 4 * i;
    float v = y_kv[(size_t)(b * 128 + 64 + c) * S_TOT + st + si];
    tile[c][si] = v * cf[192 + c] + cf[256 + c];
  }
  __syncthreads();
  float kvv[64];
#pragma unroll
  for (int c = 0; c < 64; c++) kvv[c] = tile[c][si];
  const int vsel = chunk >> 2, dq = chunk & 3;
  const float4* w4 = (const float4*)kvup_w;
  float acc[16];
#pragma unroll
  for (int d = 0; d < 16; d++) {
    int oc = h * 128 + vsel * 64 + dq * 16 + d;
    float a = kvup_b[oc];
#pragma unroll
    for (int c4 = 0; c4 < 16; c4++) {
      float4 wv = w4[oc * 16 + c4];
      a += wv.x * kvv[c4 * 4] + wv.y * kvv[c4 * 4 + 1] + wv.z * kvv[c4 * 4 + 2] + wv.w * kvv[c4 * 4 + 3];
    }
    acc[d] = a;
  }
  if (vsel == 0) {
    store_rowN<2>(krow + dq * 16, acc);
  } else {
    ushort_t* vbase = VT + (size_t)(b * 4 + h) * 64 * S_TOT + sp;
#pragma unroll
    for (int d = 0; d < 16; d++) vbase[(size_t)(dq * 16 + d) * S_TOT] = f2b(acc[d]);
  }
}

// ---------------------------------------------------------------------------
// K5: flash attention, split-KV x2, 8 waves x 16q = 128 q per block.
// Swapped-QK^T in-register softmax (exp2 domain), KV tile 64, double-buffered
// global_load_lds staging (m173 swizzle), defer-max, deferred l-reduction.
// grid 512 = 2 half x 8 bh x 32 qblk (XCD-swizzled), block 512.
// Outputs: Opart bf16 [half][bh][q][64] normalized, ml f32 [half][bh*4096+q][2].
__global__ __launch_bounds__(512, 4) void k_attn(
    const ushort_t* __restrict__ Q, const ushort_t* __restrict__ K,
    const ushort_t* __restrict__ VT, ushort_t* __restrict__ Opart,
    float* __restrict__ ml) {
  const int bid = blockIdx.x;
  const int bh = bid & 7;                  // XCD swizzle: one bh per XCD
  const int inner = bid >> 3;              // [0,64)
  const int half = inner >> 5, qblk = inner & 31;
  const int kv0 = half * 2048;
  const int tid = threadIdx.x;
  const int wid = tid >> 6, lane = tid & 63;
  const int l15 = lane & 15, lg = lane >> 4;
  const int qbase = qblk * 128 + wid * 16;
  const ushort_t* Qp = Q + (size_t)bh * S_TOT * 128;
  const ushort_t* Kp = K + (size_t)bh * S_TOT * 128;
  const ushort_t* Vp = VT + (size_t)bh * 64 * S_TOT;

  __shared__ __align__(16) ushort_t K_lds[2][64][128];  // 2 x 16 KB
  __shared__ __align__(16) ushort_t V_lds[2][64][64];   // 2 x 8 KB
  __shared__ __align__(16) ushort_t P_lds[8][16][64];   // 16 KB

  s16x8 qa[4];
#pragma unroll
  for (int kk = 0; kk < 4; kk++)
    qa[kk] = *(const s16x8*)(Qp + (size_t)(qbase + l15) * 128 + kk * 32 + lg * 8);

  f32x4 o_acc[4];
#pragma unroll
  for (int n = 0; n < 4; n++) o_acc[n] = (f32x4){0.f, 0.f, 0.f, 0.f};
  float m_s = -1e30f, l_s = 0.f;   // per-lane: m for q=l15 (row-uniform), l partial

  // staging lane constants (512 threads: 2 K loads + 1 V load each)
  const int krow_l = tid >> 4;               // 0..31, +32*i
  const int kcol_l = (tid & 15) * 16;
  const int vrow_l = tid >> 3;               // 0..63
  const int vcol_l = (tid & 7) * 16;

#define STAGE(kvb, bufi)                                                          \
  {                                                                               \
    _Pragma("unroll")                                                             \
    for (int i = 0; i < 2; i++) {                                                 \
      int row = i * 32 + krow_l;                                                  \
      int colb = kcol_l ^ ((row & 7) << 4);                                       \
      gload16((const char*)(Kp + (size_t)((kvb) + row) * 128) + colb,             \
              (void*)&K_lds[bufi][i * 32 + wid * 4][0]);                          \
    }                                                                             \
    {                                                                             \
      int colb = vcol_l ^ ((vrow_l & 7) << 4);                                    \
      gload16((const char*)(Vp + (size_t)vrow_l * S_TOT + (kvb)) + colb,          \
              (void*)&V_lds[bufi][wid * 8][0]);                                   \
    }                                                                             \
  }

  STAGE(kv0, 0);
  __syncthreads();

  const int swz = (l15 & 7) << 4;
  char* pbase = (char*)&P_lds[wid][l15][0];
#pragma unroll 1
  for (int t = 0; t < 32; t++) {
    const int buf = t & 1;
    if (t < 31) STAGE(kv0 + (t + 1) * 64, buf ^ 1);
    // swapped QK^T: sc[cb][r] = S^T[kv = cb*16+lg*4+r][q = l15]
    f32x4 sc[4];
#pragma unroll
    for (int cb = 0; cb < 4; cb++) sc[cb] = (f32x4){0.f, 0.f, 0.f, 0.f};
#pragma unroll
    for (int kk = 0; kk < 4; kk++) {
#pragma unroll
      for (int cb = 0; cb < 4; cb++) {
        const int row = cb * 16 + l15;
        const int off = (kk * 64 + lg * 16) ^ swz;
        s16x8 kf = *(const s16x8*)((const char*)&K_lds[buf][row][0] + off);
        sc[cb] = __builtin_amdgcn_mfma_f32_16x16x32_bf16(kf, qa[kk], sc[cb], 0, 0, 0);
      }
    }
    // row max: in-register tree + 2 cross-lane
    float pmax;
    {
      float a0 = fmaxf(fmaxf(sc[0][0], sc[0][1]), fmaxf(sc[0][2], sc[0][3]));
      float a1 = fmaxf(fmaxf(sc[1][0], sc[1][1]), fmaxf(sc[1][2], sc[1][3]));
      float a2 = fmaxf(fmaxf(sc[2][0], sc[2][1]), fmaxf(sc[2][2], sc[2][3]));
      float a3 = fmaxf(fmaxf(sc[3][0], sc[3][1]), fmaxf(sc[3][2], sc[3][3]));
      pmax = fmaxf(fmaxf(a0, a1), fmaxf(a2, a3));
    }
    pmax = fmaxf(pmax, xor16f(pmax));
    pmax = fmaxf(pmax, __shfl_xor(pmax, 32, 64));
    if (__any(pmax - m_s > 11.5f)) {   // defer-max
      float mn = fmaxf(m_s, pmax);
      float alpha = exp2f(m_s - mn);
      m_s = mn;
      l_s *= alpha;
      float ar[4];
#pragma unroll
      for (int r = 0; r < 4; r++) ar[r] = __shfl(alpha, lg * 4 + r, 64);
#pragma unroll
      for (int n = 0; n < 4; n++)
#pragma unroll
        for (int r = 0; r < 4; r++) o_acc[n][r] *= ar[r];
    }
    float rs = 0.f;
#pragma unroll
    for (int cb = 0; cb < 4; cb++)
#pragma unroll
      for (int r = 0; r < 4; r++) {
        float p = exp2f(sc[cb][r] - m_s);
        sc[cb][r] = p; rs += p;
      }
    l_s += rs;                        // deferred: per-lane partial only
    // P -> LDS (cvt_pk packed, swizzled): row = l15 (q), col = kv
#pragma unroll
    for (int cb = 0; cb < 4; cb++) {
      uint_t lo = cvt_pk_bf16(sc[cb][0], sc[cb][1]);
      uint_t hi = cvt_pk_bf16(sc[cb][2], sc[cb][3]);
      *(uint_t*)(pbase + ((cb * 32 + lg * 8) ^ swz)) = lo;
      *(uint_t*)(pbase + ((cb * 32 + lg * 8 + 4) ^ swz)) = hi;
    }
    asm volatile("s_waitcnt lgkmcnt(0)" ::: "memory");
    __builtin_amdgcn_sched_barrier(0);
#pragma unroll
    for (int ks = 0; ks < 2; ks++) {
      const int off = (ks * 64 + lg * 16) ^ swz;
      s16x8 pa = *(const s16x8*)(pbase + off);
#pragma unroll
      for (int n = 0; n < 4; n++) {
        s16x8 vb = *(const s16x8*)((const char*)&V_lds[buf][n * 16 + l15][0] + off);
        o_acc[n] = __builtin_amdgcn_mfma_f32_16x16x32_bf16(pa, vb, o_acc[n], 0, 0, 0);
      }
    }
    __syncthreads();
  }
#undef STAGE
  // final l reduction (row q = l15)
  l_s += xor16f(l_s);
  l_s += __shfl_xor(l_s, 32, 64);
  float linv = 1.f / l_s;
  if (lg == 0) {
    float* mlrow = ml + ((size_t)(half * 8 + bh) * S_TOT + qbase + l15) * 2;
    mlrow[0] = m_s; mlrow[1] = l_s;
  }
  float invr[4];
#pragma unroll
  for (int r = 0; r < 4; r++) invr[r] = __shfl(linv, lg * 4 + r, 64);
  ushort_t* ob = Opart + (size_t)(half * 8 + bh) * S_TOT * 64;
#pragma unroll
  for (int n = 0; n < 4; n++)
#pragma unroll
    for (int r = 0; r < 4; r++)
      ob[(size_t)(qbase + lg * 4 + r) * 64 + n * 16 + l15] = f2b(o_acc[n][r] * invr[r]);
}

// ---------------------------------------------------------------------------
// K5b: combine split-KV halves. grid 1024, block 256: 8 threads/row, 8 dims ea.
__global__ __launch_bounds__(256) void k_comb(
    const ushort_t* __restrict__ Opart, const float* __restrict__ ml,
    float* __restrict__ O) {
  const int gid = blockIdx.x * 256 + threadIdx.x;
  const int row = gid >> 3, dd = (gid & 7) * 8;   // row = bh*4096+q in [0,32768)
  const float2 ml0 = *(const float2*)&ml[(size_t)row * 2];
  const float2 ml1 = *(const float2*)&ml[(size_t)(32768 + row) * 2];
  float m = fmaxf(ml0.x, ml1.x);
  float w0 = exp2f(ml0.x - m) * ml0.y, w1 = exp2f(ml1.x - m) * ml1.y;
  float inv = 1.f / (w0 + w1);
  w0 *= inv; w1 *= inv;
  union { s16x8 v; ushort_t u[8]; } a, b;
  a.v = *(const s16x8*)&Opart[(size_t)row * 64 + dd];
  b.v = *(const s16x8*)&Opart[(size_t)2097152 + (size_t)row * 64 + dd];
  float* op = O + (size_t)row * 64 + dd;
#pragma unroll
  for (int j = 0; j < 8; j++) {
    float av = __uint_as_float((uint_t)a.u[j] << 16);
    float bv = __uint_as_float((uint_t)b.u[j] << 16);
    op[j] = w0 * av + w1 * bv;
  }
}

// ---------------------------------------------------------------------------
// K6: out conv + residual. grid B*128*4 (32-ch chunks), block 256.
__global__ __launch_bounds__(256) void k_outconv(
    const float* __restrict__ O, const float* __restrict__ out_w, const float* __restrict__ out_b,
    const float* __restrict__ x, float* __restrict__ out) {
  int id = blockIdx.x;
  const int chunk = id & 3; id >>= 2;
  const int b = id >> 7, blk = id & 127, st = blk * 32;
  const int t = threadIdx.x;
  __shared__ float o_lds[256][33];
  {
    int vd = t & 63, r0 = t >> 6;
#pragma unroll
    for (int i = 0; i < 32; i++) {
      int hs = r0 + 4 * i;
      int h = hs >> 5, ss2 = hs & 31;
      o_lds[h * 64 + vd][ss2] = O[((size_t)(b * 4 + h) * S_TOT + st + ss2) * 64 + vd];
    }
  }
  __syncthreads();
  const int si = t & 31, g = t >> 5;
  const float4* w4 = (const float4*)out_w;
#pragma unroll
  for (int i = 0; i < 4; i++) {
    int c = chunk * 32 + g + 8 * i;
    float a = out_b[c];
#pragma unroll 8
    for (int hv4 = 0; hv4 < 64; hv4++) {
      float4 wv = w4[c * 64 + hv4];
      a += wv.x * o_lds[hv4 * 4 + 0][si] + wv.y * o_lds[hv4 * 4 + 1][si]
         + wv.z * o_lds[hv4 * 4 + 2][si] + wv.w * o_lds[hv4 * 4 + 3][si];
    }
    size_t idx = (size_t)(b * 128 + c) * S_TOT + st + si;
    out[idx] = a + x[idx];
  }
}

// ---------------------------------------------------------------------------
extern "C" void kernel_launch(void* const* d_in, const int* in_sizes, int n_in,
                              void* d_out, int out_size, void* d_ws, size_t ws_size,
                              hipStream_t stream) {
  const float* x      = (const float*)d_in[0];
  const float* q1_w   = (const float*)d_in[1];
  const float* q1_b   = (const float*)d_in[2];
  const float* q_gn_g = (const float*)d_in[3];
  const float* q_gn_b = (const float*)d_in[4];
  const float* q2_w   = (const float*)d_in[5];
  const float* q2_b   = (const float*)d_in[6];
  const float* kv1_w  = (const float*)d_in[7];
  const float* kv1_b  = (const float*)d_in[8];
  const float* kv_gn_g= (const float*)d_in[9];
  const float* kv_gn_b= (const float*)d_in[10];
  const float* kvn_g  = (const float*)d_in[11];
  const float* kvn_b  = (const float*)d_in[12];
  const float* kvup_w = (const float*)d_in[13];
  const float* kvup_b = (const float*)d_in[14];
  const float* out_w  = (const float*)d_in[15];
  const float* out_b  = (const float*)d_in[16];

  const size_t MB = 1u << 20;
  char* ws = (char*)d_ws;
  float*    y_q   = (float*)(ws);                   // 0..1 MB
  float*    y_kv  = (float*)(ws + 1 * MB);          // 1..5 MB (dead after builds)
  float*    ml    = (float*)(ws + 1 * MB);          // aliases y_kv (attn->comb)
  ushort_t* Q     = (ushort_t*)(ws + 5 * MB);       // 5..13 MB
  ushort_t* K     = (ushort_t*)(ws + 13 * MB);      // 13..21 MB
  ushort_t* VT    = (ushort_t*)(ws + 21 * MB);      // 21..25 MB
  float*    O     = (float*)(ws + 25 * MB);         // 25..33 MB (written by comb)
  double*   pch   = (double*)(ws + 25 * MB);        // aliases O (dead after stats)
  float*    coef  = (float*)(ws + 27 * MB);         // aliases O (dead after builds)
  ushort_t* Opart = (ushort_t*)(ws + 33 * MB);      // 33..41.4 MB
  float*    out   = (float*)d_out;

  k_conv1  <<<512,  256, 0, stream>>>(x, q1_w, q1_b, kv1_w, kv1_b, y_q, y_kv, pch);
  k_stats  <<<1,   1024, 0, stream>>>(pch, q_gn_g, q_gn_b, kv_gn_g, kv_gn_b, kvn_g, kvn_b, coef);
  k_buildq <<<512,  256, 0, stream>>>(y_q, coef, q2_w, q2_b, Q);
  k_buildkv<<<1152, 256, 0, stream>>>(y_kv, coef, kvup_w, kvup_b, K, VT);
  k_attn   <<<512,  512, 0, stream>>>(Q, K, VT, Opart, ml);
  k_comb   <<<1024, 256, 0, stream>>>(Opart, ml, O);
  k_outconv<<<1024, 256, 0, stream>>>(O, out_w, out_b, x, out);
}

// Round 6
// 200.252 us; speedup vs baseline: 3.8655x; 1.4966x over previous
//
#include <hip/hip_runtime.h>

typedef unsigned short ushort_t;
typedef unsigned int uint_t;
typedef __attribute__((ext_vector_type(8))) short s16x8;
typedef __attribute__((ext_vector_type(4))) short s16x4;
typedef __attribute__((ext_vector_type(4))) float f32x4;

#define S_TOT 4096
#define QSCALE 0.08838834764831845f       // 1/sqrt(128)
#define LOG2E 1.4426950408889634f
#define QSL (QSCALE * LOG2E)              // baked into Q -> attn uses exp2
#define L2_10000_D16 0.8304820237218406f  // log2(10000)/16

__device__ __forceinline__ ushort_t f2b(float f) {
  uint_t u = __float_as_uint(f);
  uint_t r = (u + 0x7FFFu + ((u >> 16) & 1u)) >> 16;
  return (ushort_t)r;
}

__device__ __forceinline__ float b2f(ushort_t u) {
  return __uint_as_float((uint_t)u << 16);
}

__device__ __forceinline__ uint_t cvt_pk_bf16(float lo, float hi) {
  uint_t r;
  asm("v_cvt_pk_bf16_f32 %0, %1, %2" : "=v"(r) : "v"(lo), "v"(hi));
  return r;
}

__device__ __forceinline__ void gload16(const void* g, void* l) {
  __builtin_amdgcn_global_load_lds(
      (const __attribute__((address_space(1))) unsigned int*)g,
      (__attribute__((address_space(3))) unsigned int*)l, 16, 0, 0);
}

__device__ __forceinline__ float xor16f(float v) {
  return __int_as_float(__builtin_amdgcn_ds_swizzle(__float_as_int(v), 0x401F));
}

// one rope pair, global pair index p; (x0,x1) -> rotated * scale
__device__ __forceinline__ void rope_pair(float& x0, float& x1, int p, int hi, int wi, float scale) {
  float inv = exp2f(-(float)(p >> 1) * L2_10000_D16);
  float ang = ((p & 1) ? (float)wi : (float)hi) * inv;
  float sn = sinf(ang), cs = cosf(ang);
  float r0 = (x0 * sn - x1 * cs) * scale;
  float r1 = (x0 * cs + x1 * sn) * scale;
  x0 = r0; x1 = r1;
}

// ---------------------------------------------------------------------------
// K1: y_q = q1_w@x + b (B,32,S); y_kv = kv1_w@x + b (B,128,S)
// + per-channel per-block partials -> pch[b][blk(256)][160][2]
__global__ __launch_bounds__(256) void k_conv1(
    const float* __restrict__ x, const float* __restrict__ q1_w, const float* __restrict__ q1_b,
    const float* __restrict__ kv1_w, const float* __restrict__ kv1_b,
    float* __restrict__ y_q, float* __restrict__ y_kv, double* __restrict__ pch) {
  const int b = blockIdx.x >> 8, blk = blockIdx.x & 255, st = blk * 16;
  const int t = threadIdx.x, si = t & 15, g = t >> 4;
  __shared__ float xs[128][16];
#pragma unroll
  for (int i = 0; i < 8; i++) {
    int c = g + 16 * i;
    xs[c][si] = x[(size_t)(b * 128 + c) * S_TOT + st + si];
  }
  __syncthreads();
  float acc[10];
#pragma unroll
  for (int i = 0; i < 10; i++) {
    int oc = g * 10 + i;
    acc[i] = (oc < 32) ? q1_b[oc] : kv1_b[oc - 32];
  }
  const float4* q1w4 = (const float4*)q1_w;
  const float4* kv1w4 = (const float4*)kv1_w;
  for (int c4 = 0; c4 < 32; c4++) {
    float x0 = xs[c4 * 4 + 0][si], x1 = xs[c4 * 4 + 1][si];
    float x2 = xs[c4 * 4 + 2][si], x3 = xs[c4 * 4 + 3][si];
#pragma unroll
    for (int i = 0; i < 10; i++) {
      int oc = g * 10 + i;
      float4 wv = (oc < 32) ? q1w4[oc * 32 + c4] : kv1w4[(oc - 32) * 32 + c4];
      acc[i] += wv.x * x0 + wv.y * x1 + wv.z * x2 + wv.w * x3;
    }
  }
  double* pbase = pch + (size_t)(b * 256 + blk) * 320;
#pragma unroll
  for (int i = 0; i < 10; i++) {
    int oc = g * 10 + i;
    float a = acc[i];
    if (oc < 32) y_q[(size_t)(b * 32 + oc) * S_TOT + st + si] = a;
    else         y_kv[(size_t)(b * 128 + oc - 32) * S_TOT + st + si] = a;
    double s = a, q = (double)a * a;
#pragma unroll
    for (int o = 1; o < 16; o <<= 1) { s += __shfl_xor(s, o, 16); q += __shfl_xor(q, o, 16); }
    if (si == 0) { pbase[oc * 2] = s; pbase[oc * 2 + 1] = q; }
  }
}

// ---------------------------------------------------------------------------
// K2: reduce partials -> affine coefs; also pack GEMM weights to bf16.
__global__ __launch_bounds__(1024) void k_stats(
    const double* __restrict__ pch,
    const float* __restrict__ qg, const float* __restrict__ qb,
    const float* __restrict__ kvg, const float* __restrict__ kvb,
    const float* __restrict__ kng, const float* __restrict__ knb,
    const float* __restrict__ q2_w, const float* __restrict__ kvup_w,
    const float* __restrict__ out_w,
    float* __restrict__ coef, ushort_t* __restrict__ wq2,
    ushort_t* __restrict__ wkvup, ushort_t* __restrict__ wout) {
  const int tid = threadIdx.x;
  // weight packing (independent)
  for (int i = tid; i < 16384; i += 1024) wq2[i] = f2b(q2_w[i]);
  for (int i = tid; i < 32768; i += 1024) wkvup[i] = f2b(kvup_w[i]);
  for (int i = tid; i < 32768; i += 1024) wout[i] = f2b(out_w[i]);
  __shared__ double Sh[2][160], Qh[2][160];
  __shared__ double part[320][4][2];
  for (int work = tid; work < 1280; work += 1024) {
    int pair = work >> 2, slice = work & 3;
    int b = pair / 160, c = pair % 160;
    double s = 0, q = 0;
    const double* p = pch + (size_t)(b * 256 + slice * 64) * 320 + c * 2;
#pragma unroll 8
    for (int k = 0; k < 64; k++) { s += p[(size_t)k * 320]; q += p[(size_t)k * 320 + 1]; }
    part[pair][slice][0] = s; part[pair][slice][1] = q;
  }
  __syncthreads();
  if (tid < 320) {
    int pair = tid, b = pair / 160, c = pair % 160;
    Sh[b][c] = part[pair][0][0] + part[pair][1][0] + part[pair][2][0] + part[pair][3][0];
    Qh[b][c] = part[pair][0][1] + part[pair][1][1] + part[pair][2][1] + part[pair][3][1];
  }
  __syncthreads();
  if (tid < 2) {
    int b = tid;
    float* cf = coef + b * 320;
    const double NS = 4096.0;
    double muq = 0, m2q = 0;
    for (int c = 0; c < 32; c++) { muq += Sh[b][c]; m2q += Qh[b][c]; }
    muq /= (32.0 * NS); m2q /= (32.0 * NS);
    double rstdq = 1.0 / sqrt(m2q - muq * muq + 1e-5);
    for (int c = 0; c < 32; c++) {
      double A = rstdq * (double)qg[c];
      cf[c] = (float)A; cf[32 + c] = (float)((double)qb[c] - muq * A);
    }
    double mukv = 0, m2kv = 0;
    for (int c = 0; c < 128; c++) { mukv += Sh[b][32 + c]; m2kv += Qh[b][32 + c]; }
    mukv /= (128.0 * NS); m2kv /= (128.0 * NS);
    double rstdkv = 1.0 / sqrt(m2kv - mukv * mukv + 1e-5);
    for (int c = 0; c < 64; c++) {
      double A = rstdkv * (double)kvg[c];
      cf[64 + c] = (float)A; cf[128 + c] = (float)((double)kvb[c] - mukv * A);
    }
    double mu2 = 0, m22 = 0;
    for (int c2 = 0; c2 < 64; c2++) {
      int c = 64 + c2;
      double a = rstdkv * (double)kvg[c], bb = (double)kvb[c] - mukv * a;
      double Ec = Sh[b][32 + c] / NS, M2c = Qh[b][32 + c] / NS;
      mu2 += a * Ec + bb;
      m22 += a * a * M2c + 2.0 * a * bb * Ec + bb * bb;
    }
    mu2 /= 64.0; m22 /= 64.0;
    double rstd2 = 1.0 / sqrt(m22 - mu2 * mu2 + 1e-5);
    for (int c2 = 0; c2 < 64; c2++) {
      int c = 64 + c2;
      double a = rstdkv * (double)kvg[c], bb = (double)kvb[c] - mukv * a;
      cf[192 + c2] = (float)(a * rstd2 * (double)kng[c2]);
      cf[256 + c2] = (float)((bb - mu2) * rstd2 * (double)kng[c2] + (double)knb[c2]);
    }
  }
}

// ---------------------------------------------------------------------------
// K3: Q build as MFMA GEMM. grid B*64*4 (b, stile64, head). block 256 = 4 waves.
// out d = wid*32 + db*16 + lg*4 + r (128 d per head), K=32.
__global__ __launch_bounds__(256) void k_gq(
    const float* __restrict__ y_q, const float* __restrict__ coef,
    const ushort_t* __restrict__ wq2, const float* __restrict__ q2_b,
    ushort_t* __restrict__ Q) {
  const int id = blockIdx.x;
  const int h = id & 3, st = (id >> 2) & 63, b = id >> 8;
  const int t = threadIdx.x, si = t & 63, wid = t >> 6;
  const int l15 = t & 15, lg = (t >> 4) & 3;
  const float* cf = coef + b * 320;
  __shared__ __align__(16) ushort_t Xt[64][64];   // 8 KB (cols 0..31 used, 128B rows)
  __shared__ __align__(16) ushort_t sQ[64][128];  // 16 KB
  // stage: thread (si, wid): c = wid*8 .. +8, normalized, bf16
  {
    ushort_t pk[8];
#pragma unroll
    for (int j = 0; j < 8; j++) {
      int c = wid * 8 + j;
      float v = y_q[(size_t)(b * 32 + c) * S_TOT + st * 64 + si];
      pk[j] = f2b(v * cf[c] + cf[32 + c]);
    }
    *(s16x8*)((char*)&Xt[si][0] + ((wid * 16) ^ ((si & 7) << 4))) = *(s16x8*)pk;
  }
  __syncthreads();
  const int d0w = wid * 32;
  f32x4 acc[2][4];
#pragma unroll
  for (int db = 0; db < 2; db++) {
    f32x4 bv;
#pragma unroll
    for (int r = 0; r < 4; r++) bv[r] = q2_b[h * 128 + d0w + db * 16 + lg * 4 + r];
#pragma unroll
    for (int sb = 0; sb < 4; sb++) acc[db][sb] = bv;
  }
  s16x8 wf[2];
#pragma unroll
  for (int db = 0; db < 2; db++)
    wf[db] = *(const s16x8*)(wq2 + (size_t)(h * 128 + d0w + db * 16 + l15) * 32 + lg * 8);
  const int xsw = (lg * 16) ^ ((l15 & 7) << 4);
#pragma unroll
  for (int sb = 0; sb < 4; sb++) {
    s16x8 xf = *(const s16x8*)((const char*)&Xt[sb * 16 + l15][0] + xsw);
#pragma unroll
    for (int db = 0; db < 2; db++)
      acc[db][sb] = __builtin_amdgcn_mfma_f32_16x16x32_bf16(wf[db], xf, acc[db][sb], 0, 0, 0);
  }
  // epilogue: rope (waves 2,3) or scale, bounce through sQ
  if (wid >= 2) {
#pragma unroll
    for (int db = 0; db < 2; db++)
#pragma unroll
      for (int sb = 0; sb < 4; sb++) {
        int sp = st * 64 + sb * 16 + l15, hi = sp >> 6, wi = sp & 63;
        int dg = d0w + db * 16 + lg * 4;
#pragma unroll
        for (int pr = 0; pr < 2; pr++) {
          float v0 = acc[db][sb][pr * 2], v1 = acc[db][sb][pr * 2 + 1];
          int p = (dg + pr * 2 - 64) >> 1;
          rope_pair(v0, v1, p, hi, wi, QSL);
          acc[db][sb][pr * 2] = v0; acc[db][sb][pr * 2 + 1] = v1;
        }
      }
  } else {
#pragma unroll
    for (int db = 0; db < 2; db++)
#pragma unroll
      for (int sb = 0; sb < 4; sb++)
#pragma unroll
        for (int r = 0; r < 4; r++) acc[db][sb][r] *= QSL;
  }
#pragma unroll
  for (int db = 0; db < 2; db++)
#pragma unroll
    for (int sb = 0; sb < 4; sb++) {
      ushort_t pk[4];
#pragma unroll
      for (int r = 0; r < 4; r++) pk[r] = f2b(acc[db][sb][r]);
      int srow = sb * 16 + l15;
      *(s16x4*)((char*)&sQ[srow][0] + (((d0w + db * 16 + lg * 4) * 2) ^ ((srow & 7) << 4))) =
          *(s16x4*)pk;
    }
  __syncthreads();
  // coalesced store: thread (si, wid): d = wid*32..+32 of row sp
  ushort_t* qrow = Q + ((size_t)(b * 4 + h) * S_TOT + st * 64 + si) * 128 + wid * 32;
#pragma unroll
  for (int j = 0; j < 4; j++) {
    s16x8 v = *(const s16x8*)((const char*)&sQ[si][0] + ((wid * 64 + j * 16) ^ ((si & 7) << 4)));
    *(s16x8*)(qrow + j * 8) = v;
  }
}

// ---------------------------------------------------------------------------
// K4: KV build as MFMA GEMM + fused k_rope. grid B*64*4. block 256 = 4 waves.
// waves 0,1: k_nope (dn = wid*32+..) -> bounce sK; waves 2,3: v -> direct VT.
// store phase also computes rope'd K dims 64..127.
__global__ __launch_bounds__(256) void k_gkv(
    const float* __restrict__ y_kv, const float* __restrict__ coef,
    const ushort_t* __restrict__ wkvup, const float* __restrict__ kvup_b,
    ushort_t* __restrict__ K, ushort_t* __restrict__ VT) {
  const int id = blockIdx.x;
  const int h = id & 3, st = (id >> 2) & 63, b = id >> 8;
  const int t = threadIdx.x, si = t & 63, wid = t >> 6;
  const int l15 = t & 15, lg = (t >> 4) & 3;
  const float* cf = coef + b * 320;
  __shared__ __align__(16) ushort_t Xt[64][64];  // 8 KB (kvn normalized)
  __shared__ __align__(16) ushort_t sK[64][64];  // 8 KB (k_nope)
  // stage: thread (si, wid): c2 = wid*16..+16
  {
#pragma unroll
    for (int half = 0; half < 2; half++) {
      ushort_t pk[8];
#pragma unroll
      for (int j = 0; j < 8; j++) {
        int c2 = wid * 16 + half * 8 + j;
        float v = y_kv[(size_t)(b * 128 + 64 + c2) * S_TOT + st * 64 + si];
        pk[j] = f2b(v * cf[192 + c2] + cf[256 + c2]);
      }
      *(s16x8*)((char*)&Xt[si][0] + ((wid * 32 + half * 16) ^ ((si & 7) << 4))) = *(s16x8*)pk;
    }
  }
  __syncthreads();
  const int d0w = wid * 32;   // 0..127: <64 k_nope, >=64 v
  f32x4 acc[2][4];
#pragma unroll
  for (int db = 0; db < 2; db++) {
    f32x4 bv;
#pragma unroll
    for (int r = 0; r < 4; r++) bv[r] = kvup_b[h * 128 + d0w + db * 16 + lg * 4 + r];
#pragma unroll
    for (int sb = 0; sb < 4; sb++) acc[db][sb] = bv;
  }
  s16x8 wf[2][2];
#pragma unroll
  for (int db = 0; db < 2; db++)
#pragma unroll
    for (int kk = 0; kk < 2; kk++)
      wf[db][kk] = *(const s16x8*)(wkvup + (size_t)(h * 128 + d0w + db * 16 + l15) * 64 +
                                   kk * 32 + lg * 8);
#pragma unroll
  for (int sb = 0; sb < 4; sb++) {
#pragma unroll
    for (int kk = 0; kk < 2; kk++) {
      s16x8 xf = *(const s16x8*)((const char*)&Xt[sb * 16 + l15][0] +
                                 ((kk * 64 + lg * 16) ^ ((l15 & 7) << 4)));
#pragma unroll
      for (int db = 0; db < 2; db++)
        acc[db][sb] = __builtin_amdgcn_mfma_f32_16x16x32_bf16(wf[db][kk], xf, acc[db][sb], 0, 0, 0);
    }
  }
  if (wid < 2) {
    // k_nope -> sK bounce
#pragma unroll
    for (int db = 0; db < 2; db++)
#pragma unroll
      for (int sb = 0; sb < 4; sb++) {
        ushort_t pk[4];
#pragma unroll
        for (int r = 0; r < 4; r++) pk[r] = f2b(acc[db][sb][r]);
        int srow = sb * 16 + l15;
        *(s16x4*)((char*)&sK[srow][0] + (((d0w + db * 16 + lg * 4) * 2) ^ ((srow & 7) << 4))) =
            *(s16x4*)pk;
      }
  } else {
    // v -> direct VT[(b*4+h)][vd][sp] (quarter-wave coalesced 2B stores)
    ushort_t* vb = VT + (size_t)(b * 4 + h) * 64 * S_TOT;
#pragma unroll
    for (int db = 0; db < 2; db++)
#pragma unroll
      for (int sb = 0; sb < 4; sb++) {
        int sp = st * 64 + sb * 16 + l15;
#pragma unroll
        for (int r = 0; r < 4; r++) {
          int vd = (wid - 2) * 32 + db * 16 + lg * 4 + r;
          vb[(size_t)vd * S_TOT + sp] = f2b(acc[db][sb][r]);
        }
      }
  }
  __syncthreads();
  // store phase: thread (si, wid): K row sp = st*64+si: k_nope dims wid*16..+16
  const int sp = st * 64 + si;
  ushort_t* krow = K + ((size_t)(b * 4 + h) * S_TOT + sp) * 128;
#pragma unroll
  for (int j = 0; j < 2; j++) {
    s16x8 v = *(const s16x8*)((const char*)&sK[si][0] + ((wid * 32 + j * 16) ^ ((si & 7) << 4)));
    *(s16x8*)(krow + wid * 16 + j * 8) = v;
  }
  // fused k_rope: ch c = wid*16..+16 (global rope channels), store dims 64+c
  {
    const int c0 = wid * 16, hi = sp >> 6, wi = sp & 63;
    float v[16];
#pragma unroll
    for (int j = 0; j < 16; j++) {
      int c = c0 + j;
      v[j] = y_kv[(size_t)(b * 128 + c) * S_TOT + sp] * cf[64 + c] + cf[128 + c];
    }
#pragma unroll
    for (int k = 0; k < 8; k++) {
      int p = (c0 >> 1) + k;
      rope_pair(v[2 * k], v[2 * k + 1], p, hi, wi, 1.0f);
    }
    ushort_t pk[16];
#pragma unroll
    for (int j = 0; j < 16; j++) pk[j] = f2b(v[j]);
    *(s16x8*)(krow + 64 + c0) = *(s16x8*)pk;
    *(s16x8*)(krow + 64 + c0 + 8) = *(s16x8*)(pk + 8);
  }
}

// ---------------------------------------------------------------------------
// K5: flash attention (round-4 structure + setprio around MFMA clusters).
__global__ __launch_bounds__(512, 4) void k_attn(
    const ushort_t* __restrict__ Q, const ushort_t* __restrict__ K,
    const ushort_t* __restrict__ VT, ushort_t* __restrict__ Opart,
    float* __restrict__ ml) {
  const int bid = blockIdx.x;
  const int bh = bid & 7;
  const int inner = bid >> 3;
  const int half = inner >> 5, qblk = inner & 31;
  const int kv0 = half * 2048;
  const int tid = threadIdx.x;
  const int wid = tid >> 6, lane = tid & 63;
  const int l15 = lane & 15, lg = lane >> 4;
  const int qbase = qblk * 128 + wid * 16;
  const ushort_t* Qp = Q + (size_t)bh * S_TOT * 128;
  const ushort_t* Kp = K + (size_t)bh * S_TOT * 128;
  const ushort_t* Vp = VT + (size_t)bh * 64 * S_TOT;

  __shared__ __align__(16) ushort_t K_lds[2][64][128];
  __shared__ __align__(16) ushort_t V_lds[2][64][64];
  __shared__ __align__(16) ushort_t P_lds[8][16][64];

  s16x8 qa[4];
#pragma unroll
  for (int kk = 0; kk < 4; kk++)
    qa[kk] = *(const s16x8*)(Qp + (size_t)(qbase + l15) * 128 + kk * 32 + lg * 8);

  f32x4 o_acc[4];
#pragma unroll
  for (int n = 0; n < 4; n++) o_acc[n] = (f32x4){0.f, 0.f, 0.f, 0.f};
  float m_s = -1e30f, l_s = 0.f;

  const int krow_l = tid >> 4;
  const int kcol_l = (tid & 15) * 16;
  const int vrow_l = tid >> 3;
  const int vcol_l = (tid & 7) * 16;

#define STAGE(kvb, bufi)                                                          \
  {                                                                               \
    _Pragma("unroll")                                                             \
    for (int i = 0; i < 2; i++) {                                                 \
      int row = i * 32 + krow_l;                                                  \
      int colb = kcol_l ^ ((row & 7) << 4);                                       \
      gload16((const char*)(Kp + (size_t)((kvb) + row) * 128) + colb,             \
              (void*)&K_lds[bufi][i * 32 + wid * 4][0]);                          \
    }                                                                             \
    {                                                                             \
      int colb = vcol_l ^ ((vrow_l & 7) << 4);                                    \
      gload16((const char*)(Vp + (size_t)vrow_l * S_TOT + (kvb)) + colb,          \
              (void*)&V_lds[bufi][wid * 8][0]);                                   \
    }                                                                             \
  }

  STAGE(kv0, 0);
  __syncthreads();

  const int swz = (l15 & 7) << 4;
  char* pbase = (char*)&P_lds[wid][l15][0];
#pragma unroll 1
  for (int t = 0; t < 32; t++) {
    const int buf = t & 1;
    if (t < 31) STAGE(kv0 + (t + 1) * 64, buf ^ 1);
    f32x4 sc[4];
#pragma unroll
    for (int cb = 0; cb < 4; cb++) sc[cb] = (f32x4){0.f, 0.f, 0.f, 0.f};
    __builtin_amdgcn_s_setprio(1);
#pragma unroll
    for (int kk = 0; kk < 4; kk++) {
#pragma unroll
      for (int cb = 0; cb < 4; cb++) {
        const int row = cb * 16 + l15;
        const int off = (kk * 64 + lg * 16) ^ swz;
        s16x8 kf = *(const s16x8*)((const char*)&K_lds[buf][row][0] + off);
        sc[cb] = __builtin_amdgcn_mfma_f32_16x16x32_bf16(kf, qa[kk], sc[cb], 0, 0, 0);
      }
    }
    __builtin_amdgcn_s_setprio(0);
    float pmax;
    {
      float a0 = fmaxf(fmaxf(sc[0][0], sc[0][1]), fmaxf(sc[0][2], sc[0][3]));
      float a1 = fmaxf(fmaxf(sc[1][0], sc[1][1]), fmaxf(sc[1][2], sc[1][3]));
      float a2 = fmaxf(fmaxf(sc[2][0], sc[2][1]), fmaxf(sc[2][2], sc[2][3]));
      float a3 = fmaxf(fmaxf(sc[3][0], sc[3][1]), fmaxf(sc[3][2], sc[3][3]));
      pmax = fmaxf(fmaxf(a0, a1), fmaxf(a2, a3));
    }
    pmax = fmaxf(pmax, xor16f(pmax));
    pmax = fmaxf(pmax, __shfl_xor(pmax, 32, 64));
    if (__any(pmax - m_s > 11.5f)) {
      float mn = fmaxf(m_s, pmax);
      float alpha = exp2f(m_s - mn);
      m_s = mn;
      l_s *= alpha;
      float ar[4];
#pragma unroll
      for (int r = 0; r < 4; r++) ar[r] = __shfl(alpha, lg * 4 + r, 64);
#pragma unroll
      for (int n = 0; n < 4; n++)
#pragma unroll
        for (int r = 0; r < 4; r++) o_acc[n][r] *= ar[r];
    }
    float rs = 0.f;
#pragma unroll
    for (int cb = 0; cb < 4; cb++)
#pragma unroll
      for (int r = 0; r < 4; r++) {
        float p = exp2f(sc[cb][r] - m_s);
        sc[cb][r] = p; rs += p;
      }
    l_s += rs;
#pragma unroll
    for (int cb = 0; cb < 4; cb++) {
      uint_t lo = cvt_pk_bf16(sc[cb][0], sc[cb][1]);
      uint_t hi = cvt_pk_bf16(sc[cb][2], sc[cb][3]);
      *(uint_t*)(pbase + ((cb * 32 + lg * 8) ^ swz)) = lo;
      *(uint_t*)(pbase + ((cb * 32 + lg * 8 + 4) ^ swz)) = hi;
    }
    asm volatile("s_waitcnt lgkmcnt(0)" ::: "memory");
    __builtin_amdgcn_sched_barrier(0);
    __builtin_amdgcn_s_setprio(1);
#pragma unroll
    for (int ks = 0; ks < 2; ks++) {
      const int off = (ks * 64 + lg * 16) ^ swz;
      s16x8 pa = *(const s16x8*)(pbase + off);
#pragma unroll
      for (int n = 0; n < 4; n++) {
        s16x8 vb = *(const s16x8*)((const char*)&V_lds[buf][n * 16 + l15][0] + off);
        o_acc[n] = __builtin_amdgcn_mfma_f32_16x16x32_bf16(pa, vb, o_acc[n], 0, 0, 0);
      }
    }
    __builtin_amdgcn_s_setprio(0);
    __syncthreads();
  }
#undef STAGE
  l_s += xor16f(l_s);
  l_s += __shfl_xor(l_s, 32, 64);
  float linv = 1.f / l_s;
  if (lg == 0) {
    float* mlrow = ml + ((size_t)(half * 8 + bh) * S_TOT + qbase + l15) * 2;
    mlrow[0] = m_s; mlrow[1] = l_s;
  }
  float invr[4];
#pragma unroll
  for (int r = 0; r < 4; r++) invr[r] = __shfl(linv, lg * 4 + r, 64);
  ushort_t* ob = Opart + (size_t)(half * 8 + bh) * S_TOT * 64;
#pragma unroll
  for (int n = 0; n < 4; n++)
#pragma unroll
    for (int r = 0; r < 4; r++)
      ob[(size_t)(qbase + lg * 4 + r) * 64 + n * 16 + l15] = f2b(o_acc[n][r] * invr[r]);
}

// ---------------------------------------------------------------------------
// K6: out conv as MFMA GEMM with fused split-KV combine + residual.
// grid B*128*2 (b, stile32, cchunk64). block 256 = 4 waves x 16 c x 32 s. K=256.
__global__ __launch_bounds__(256) void k_oc(
    const ushort_t* __restrict__ Opart, const float* __restrict__ ml,
    const ushort_t* __restrict__ wout, const float* __restrict__ out_b,
    const float* __restrict__ x, float* __restrict__ out) {
  const int id = blockIdx.x;
  const int cch = id & 1, st32 = (id >> 1) & 127, b = id >> 8;
  const int t = threadIdx.x, wid = t >> 6;
  const int l15 = t & 15, lg = (t >> 4) & 3;
  __shared__ __align__(16) ushort_t Xt[32][256];  // 16 KB combined O^T tile
  // stage+combine: thread (s = t&31, grp = t>>5): c = grp*32..+32
  {
    const int s = t & 31, grp = t >> 5;
    const int h = grp >> 1, vd0 = (grp & 1) * 32;
    const int sp = st32 * 32 + s;
    const float2 ml0 = *(const float2*)&ml[((size_t)(b * 4 + h) * S_TOT + sp) * 2];
    const float2 ml1 = *(const float2*)&ml[((size_t)(8 + b * 4 + h) * S_TOT + sp) * 2];
    float mm = fmaxf(ml0.x, ml1.x);
    float w0 = exp2f(ml0.x - mm) * ml0.y, w1 = exp2f(ml1.x - mm) * ml1.y;
    float inv = 1.f / (w0 + w1);
    w0 *= inv; w1 *= inv;
    const ushort_t* oa = Opart + ((size_t)(b * 4 + h) * S_TOT + sp) * 64 + vd0;
    const ushort_t* obp = oa + (size_t)8 * S_TOT * 64;
#pragma unroll
    for (int j4 = 0; j4 < 4; j4++) {
      union { s16x8 v; ushort_t u[8]; } av, bv2;
      av.v = *(const s16x8*)(oa + j4 * 8);
      bv2.v = *(const s16x8*)(obp + j4 * 8);
      ushort_t pk[8];
#pragma unroll
      for (int j = 0; j < 8; j++) pk[j] = f2b(w0 * b2f(av.u[j]) + w1 * b2f(bv2.u[j]));
      *(s16x8*)((char*)&Xt[s][0] + ((grp * 64 + j4 * 16) ^ ((s & 7) << 4))) = *(s16x8*)pk;
    }
  }
  __syncthreads();
  const int c0w = cch * 64 + wid * 16;
  f32x4 acc[2];
  {
    f32x4 bv;
#pragma unroll
    for (int r = 0; r < 4; r++) bv[r] = out_b[c0w + lg * 4 + r];
    acc[0] = bv; acc[1] = bv;
  }
#pragma unroll
  for (int kk = 0; kk < 8; kk++) {
    s16x8 wf = *(const s16x8*)(wout + (size_t)(c0w + l15) * 256 + kk * 32 + lg * 8);
#pragma unroll
    for (int sb = 0; sb < 2; sb++) {
      s16x8 xf = *(const s16x8*)((const char*)&Xt[sb * 16 + l15][0] +
                                 ((kk * 64 + lg * 16) ^ ((l15 & 7) << 4)));
      acc[sb] = __builtin_amdgcn_mfma_f32_16x16x32_bf16(wf, xf, acc[sb], 0, 0, 0);
    }
  }
  // epilogue: + x, direct f32 stores (16-lane coalesced 64B)
#pragma unroll
  for (int sb = 0; sb < 2; sb++) {
#pragma unroll
    for (int r = 0; r < 4; r++) {
      int c = c0w + lg * 4 + r;
      int sp = st32 * 32 + sb * 16 + l15;
      size_t idx = (size_t)(b * 128 + c) * S_TOT + sp;
      out[idx] = acc[sb][r] + x[idx];
    }
  }
}

// ---------------------------------------------------------------------------
extern "C" void kernel_launch(void* const* d_in, const int* in_sizes, int n_in,
                              void* d_out, int out_size, void* d_ws, size_t ws_size,
                              hipStream_t stream) {
  const float* x      = (const float*)d_in[0];
  const float* q1_w   = (const float*)d_in[1];
  const float* q1_b   = (const float*)d_in[2];
  const float* q_gn_g = (const float*)d_in[3];
  const float* q_gn_b = (const float*)d_in[4];
  const float* q2_w   = (const float*)d_in[5];
  const float* q2_b   = (const float*)d_in[6];
  const float* kv1_w  = (const float*)d_in[7];
  const float* kv1_b  = (const float*)d_in[8];
  const float* kv_gn_g= (const float*)d_in[9];
  const float* kv_gn_b= (const float*)d_in[10];
  const float* kvn_g  = (const float*)d_in[11];
  const float* kvn_b  = (const float*)d_in[12];
  const float* kvup_w = (const float*)d_in[13];
  const float* kvup_b = (const float*)d_in[14];
  const float* out_w  = (const float*)d_in[15];
  const float* out_b  = (const float*)d_in[16];

  const size_t MB = 1u << 20;
  char* ws = (char*)d_ws;
  float*    y_q   = (float*)(ws);                    // 0..1 MB
  float*    y_kv  = (float*)(ws + 1 * MB);           // 1..5 MB
  ushort_t* Q     = (ushort_t*)(ws + 5 * MB);        // 5..13 MB
  ushort_t* K     = (ushort_t*)(ws + 13 * MB);       // 13..21 MB
  ushort_t* VT    = (ushort_t*)(ws + 21 * MB);       // 21..25 MB
  double*   pch   = (double*)(ws + 25 * MB);         // 25..26.4 MB
  float*    coef  = (float*)(ws + 27 * MB);          // 2.5 KB
  ushort_t* wq2   = (ushort_t*)(ws + 27 * MB + 65536);    // 32 KB
  ushort_t* wkvup = (ushort_t*)(ws + 27 * MB + 131072);   // 64 KB
  ushort_t* wout  = (ushort_t*)(ws + 27 * MB + 262144);   // 64 KB
  ushort_t* Opart = (ushort_t*)(ws + 29 * MB);       // 29..37.4 MB
  float*    ml    = (float*)(ws + 38 * MB);          // 0.5 MB
  float*    out   = (float*)d_out;

  k_conv1<<<512, 256, 0, stream>>>(x, q1_w, q1_b, kv1_w, kv1_b, y_q, y_kv, pch);
  k_stats<<<1, 1024, 0, stream>>>(pch, q_gn_g, q_gn_b, kv_gn_g, kv_gn_b, kvn_g, kvn_b,
                                  q2_w, kvup_w, out_w, coef, wq2, wkvup, wout);
  k_gq   <<<512, 256, 0, stream>>>(y_q, coef, wq2, q2_b, Q);
  k_gkv  <<<512, 256, 0, stream>>>(y_kv, coef, wkvup, kvup_b, K, VT);
  k_attn <<<512, 512, 0, stream>>>(Q, K, VT, Opart, ml);
  k_oc   <<<512, 256, 0, stream>>>(Opart, ml, wout, out_b, x, out);
}

// Round 8
// 152.512 us; speedup vs baseline: 5.0755x; 1.3130x over previous
//
#include <hip/hip_runtime.h>

typedef unsigned short ushort_t;
typedef unsigned int uint_t;
typedef __attribute__((ext_vector_type(8))) short s16x8;
typedef __attribute__((ext_vector_type(4))) short s16x4;
typedef __attribute__((ext_vector_type(4))) float f32x4;
typedef __attribute__((ext_vector_type(16))) float f32x16;

#define S_TOT 4096
#define QSCALE 0.08838834764831845f       // 1/sqrt(128)
#define LOG2E 1.4426950408889634f
#define QSL (QSCALE * LOG2E)              // baked into Q -> attn uses exp2
#define L2_10000_D16 0.8304820237218406f  // log2(10000)/16

__device__ __forceinline__ ushort_t f2b(float f) {
  uint_t u = __float_as_uint(f);
  uint_t r = (u + 0x7FFFu + ((u >> 16) & 1u)) >> 16;
  return (ushort_t)r;
}

__device__ __forceinline__ float b2f(ushort_t u) {
  return __uint_as_float((uint_t)u << 16);
}

__device__ __forceinline__ uint_t cvt_pk_bf16(float lo, float hi) {
  uint_t r;
  asm("v_cvt_pk_bf16_f32 %0, %1, %2" : "=v"(r) : "v"(lo), "v"(hi));
  return r;
}

__device__ __forceinline__ void gload16(const void* g, void* l) {
  __builtin_amdgcn_global_load_lds(
      (const __attribute__((address_space(1))) unsigned int*)g,
      (__attribute__((address_space(3))) unsigned int*)l, 16, 0, 0);
}

// one rope pair, global pair index p; (x0,x1) -> rotated * scale
__device__ __forceinline__ void rope_pair(float& x0, float& x1, int p, int hi, int wi, float scale) {
  float inv = exp2f(-(float)(p >> 1) * L2_10000_D16);
  float ang = ((p & 1) ? (float)wi : (float)hi) * inv;
  float sn = sinf(ang), cs = cosf(ang);
  float r0 = (x0 * sn - x1 * cs) * scale;
  float r1 = (x0 * cs + x1 * sn) * scale;
  x0 = r0; x1 = r1;
}

// ---------------------------------------------------------------------------
// K1: blocks 0..511: y_q = q1_w@x + b; y_kv = kv1_w@x + b; per-channel
// per-block partials -> pch. blocks 512..831: bf16 weight packing (fused).
__global__ __launch_bounds__(256) void k_conv1(
    const float* __restrict__ x, const float* __restrict__ q1_w, const float* __restrict__ q1_b,
    const float* __restrict__ kv1_w, const float* __restrict__ kv1_b,
    float* __restrict__ y_q, float* __restrict__ y_kv, double* __restrict__ pch,
    const float* __restrict__ q2_w, const float* __restrict__ kvup_w,
    const float* __restrict__ out_w, ushort_t* __restrict__ wq2,
    ushort_t* __restrict__ wkvup, ushort_t* __restrict__ wout) {
  if (blockIdx.x >= 512) {
    int i = (blockIdx.x - 512) * 256 + threadIdx.x;
    if (i < 16384) wq2[i] = f2b(q2_w[i]);
    else if (i < 49152) wkvup[i - 16384] = f2b(kvup_w[i - 16384]);
    else if (i < 81920) wout[i - 49152] = f2b(out_w[i - 49152]);
    return;
  }
  const int b = blockIdx.x >> 8, blk = blockIdx.x & 255, st = blk * 16;
  const int t = threadIdx.x, si = t & 15, g = t >> 4;
  __shared__ float xs[128][16];
#pragma unroll
  for (int i = 0; i < 8; i++) {
    int c = g + 16 * i;
    xs[c][si] = x[(size_t)(b * 128 + c) * S_TOT + st + si];
  }
  __syncthreads();
  float acc[10];
#pragma unroll
  for (int i = 0; i < 10; i++) {
    int oc = g * 10 + i;
    acc[i] = (oc < 32) ? q1_b[oc] : kv1_b[oc - 32];
  }
  const float4* q1w4 = (const float4*)q1_w;
  const float4* kv1w4 = (const float4*)kv1_w;
  for (int c4 = 0; c4 < 32; c4++) {
    float x0 = xs[c4 * 4 + 0][si], x1 = xs[c4 * 4 + 1][si];
    float x2 = xs[c4 * 4 + 2][si], x3 = xs[c4 * 4 + 3][si];
#pragma unroll
    for (int i = 0; i < 10; i++) {
      int oc = g * 10 + i;
      float4 wv = (oc < 32) ? q1w4[oc * 32 + c4] : kv1w4[(oc - 32) * 32 + c4];
      acc[i] += wv.x * x0 + wv.y * x1 + wv.z * x2 + wv.w * x3;
    }
  }
  double* pbase = pch + (size_t)(b * 256 + blk) * 320;
#pragma unroll
  for (int i = 0; i < 10; i++) {
    int oc = g * 10 + i;
    float a = acc[i];
    if (oc < 32) y_q[(size_t)(b * 32 + oc) * S_TOT + st + si] = a;
    else         y_kv[(size_t)(b * 128 + oc - 32) * S_TOT + st + si] = a;
    double s = a, q = (double)a * a;
#pragma unroll
    for (int o = 1; o < 16; o <<= 1) { s += __shfl_xor(s, o, 16); q += __shfl_xor(q, o, 16); }
    if (si == 0) { pbase[oc * 2] = s; pbase[oc * 2 + 1] = q; }
  }
}

// ---------------------------------------------------------------------------
// K2b: parallel reduction of pch over blk axis. grid 320 (pair = b*160+c).
__global__ __launch_bounds__(256) void k_red(
    const double* __restrict__ pch, double* __restrict__ SQ) {
  const int pair = blockIdx.x;
  const int b = pair / 160, c = pair % 160;
  const int tid = threadIdx.x;
  __shared__ double rs[256], rq[256];
  rs[tid] = pch[(size_t)(b * 256 + tid) * 320 + c * 2];
  rq[tid] = pch[(size_t)(b * 256 + tid) * 320 + c * 2 + 1];
  __syncthreads();
#pragma unroll
  for (int o = 128; o > 0; o >>= 1) {
    if (tid < o) { rs[tid] += rs[tid + o]; rq[tid] += rq[tid + o]; }
    __syncthreads();
  }
  if (tid == 0) { SQ[pair * 2] = rs[0]; SQ[pair * 2 + 1] = rq[0]; }
}

// K2c: compose group-norms into per-channel affine coefs.
// BUGFIX (round 6): was launched with 256 threads but loads needed tid<320.
// Now 512 threads so all 320 (b,c) moments are loaded into LDS.
__global__ __launch_bounds__(512) void k_stats(
    const double* __restrict__ SQ,
    const float* __restrict__ qg, const float* __restrict__ qb,
    const float* __restrict__ kvg, const float* __restrict__ kvb,
    const float* __restrict__ kng, const float* __restrict__ knb,
    float* __restrict__ coef) {
  __shared__ double Sh[2][160], Qh[2][160];
  const int tid = threadIdx.x;
  if (tid < 320) {
    int b = tid / 160, c = tid % 160;
    Sh[b][c] = SQ[tid * 2]; Qh[b][c] = SQ[tid * 2 + 1];
  }
  __syncthreads();
  if (tid < 2) {
    int b = tid;
    float* cf = coef + b * 320;
    const double NS = 4096.0;
    double muq = 0, m2q = 0;
    for (int c = 0; c < 32; c++) { muq += Sh[b][c]; m2q += Qh[b][c]; }
    muq /= (32.0 * NS); m2q /= (32.0 * NS);
    double rstdq = 1.0 / sqrt(m2q - muq * muq + 1e-5);
    for (int c = 0; c < 32; c++) {
      double A = rstdq * (double)qg[c];
      cf[c] = (float)A; cf[32 + c] = (float)((double)qb[c] - muq * A);
    }
    double mukv = 0, m2kv = 0;
    for (int c = 0; c < 128; c++) { mukv += Sh[b][32 + c]; m2kv += Qh[b][32 + c]; }
    mukv /= (128.0 * NS); m2kv /= (128.0 * NS);
    double rstdkv = 1.0 / sqrt(m2kv - mukv * mukv + 1e-5);
    for (int c = 0; c < 64; c++) {
      double A = rstdkv * (double)kvg[c];
      cf[64 + c] = (float)A; cf[128 + c] = (float)((double)kvb[c] - mukv * A);
    }
    double mu2 = 0, m22 = 0;
    for (int c2 = 0; c2 < 64; c2++) {
      int c = 64 + c2;
      double a = rstdkv * (double)kvg[c], bb = (double)kvb[c] - mukv * a;
      double Ec = Sh[b][32 + c] / NS, M2c = Qh[b][32 + c] / NS;
      mu2 += a * Ec + bb;
      m22 += a * a * M2c + 2.0 * a * bb * Ec + bb * bb;
    }
    mu2 /= 64.0; m22 /= 64.0;
    double rstd2 = 1.0 / sqrt(m22 - mu2 * mu2 + 1e-5);
    for (int c2 = 0; c2 < 64; c2++) {
      int c = 64 + c2;
      double a = rstdkv * (double)kvg[c], bb = (double)kvb[c] - mukv * a;
      cf[192 + c2] = (float)(a * rstd2 * (double)kng[c2]);
      cf[256 + c2] = (float)((bb - mu2) * rstd2 * (double)kng[c2] + (double)knb[c2]);
    }
  }
}

// ---------------------------------------------------------------------------
// K3: Q build as MFMA GEMM. grid B*64*4 (b, stile64, head). block 256 = 4 waves.
__global__ __launch_bounds__(256) void k_gq(
    const float* __restrict__ y_q, const float* __restrict__ coef,
    const ushort_t* __restrict__ wq2, const float* __restrict__ q2_b,
    ushort_t* __restrict__ Q) {
  const int id = blockIdx.x;
  const int h = id & 3, st = (id >> 2) & 63, b = id >> 8;
  const int t = threadIdx.x, si = t & 63, wid = t >> 6;
  const int l15 = t & 15, lg = (t >> 4) & 3;
  const float* cf = coef + b * 320;
  __shared__ __align__(16) ushort_t Xt[64][64];
  __shared__ __align__(16) ushort_t sQ[64][128];
  {
    ushort_t pk[8];
#pragma unroll
    for (int j = 0; j < 8; j++) {
      int c = wid * 8 + j;
      float v = y_q[(size_t)(b * 32 + c) * S_TOT + st * 64 + si];
      pk[j] = f2b(v * cf[c] + cf[32 + c]);
    }
    *(s16x8*)((char*)&Xt[si][0] + ((wid * 16) ^ ((si & 7) << 4))) = *(s16x8*)pk;
  }
  __syncthreads();
  const int d0w = wid * 32;
  f32x4 acc[2][4];
#pragma unroll
  for (int db = 0; db < 2; db++) {
    f32x4 bv;
#pragma unroll
    for (int r = 0; r < 4; r++) bv[r] = q2_b[h * 128 + d0w + db * 16 + lg * 4 + r];
#pragma unroll
    for (int sb = 0; sb < 4; sb++) acc[db][sb] = bv;
  }
  s16x8 wf[2];
#pragma unroll
  for (int db = 0; db < 2; db++)
    wf[db] = *(const s16x8*)(wq2 + (size_t)(h * 128 + d0w + db * 16 + l15) * 32 + lg * 8);
  const int xsw = (lg * 16) ^ ((l15 & 7) << 4);
#pragma unroll
  for (int sb = 0; sb < 4; sb++) {
    s16x8 xf = *(const s16x8*)((const char*)&Xt[sb * 16 + l15][0] + xsw);
#pragma unroll
    for (int db = 0; db < 2; db++)
      acc[db][sb] = __builtin_amdgcn_mfma_f32_16x16x32_bf16(wf[db], xf, acc[db][sb], 0, 0, 0);
  }
  if (wid >= 2) {
#pragma unroll
    for (int db = 0; db < 2; db++)
#pragma unroll
      for (int sb = 0; sb < 4; sb++) {
        int sp = st * 64 + sb * 16 + l15, hi = sp >> 6, wi = sp & 63;
        int dg = d0w + db * 16 + lg * 4;
#pragma unroll
        for (int pr = 0; pr < 2; pr++) {
          float v0 = acc[db][sb][pr * 2], v1 = acc[db][sb][pr * 2 + 1];
          int p = (dg + pr * 2 - 64) >> 1;
          rope_pair(v0, v1, p, hi, wi, QSL);
          acc[db][sb][pr * 2] = v0; acc[db][sb][pr * 2 + 1] = v1;
        }
      }
  } else {
#pragma unroll
    for (int db = 0; db < 2; db++)
#pragma unroll
      for (int sb = 0; sb < 4; sb++)
#pragma unroll
        for (int r = 0; r < 4; r++) acc[db][sb][r] *= QSL;
  }
#pragma unroll
  for (int db = 0; db < 2; db++)
#pragma unroll
    for (int sb = 0; sb < 4; sb++) {
      ushort_t pk[4];
#pragma unroll
      for (int r = 0; r < 4; r++) pk[r] = f2b(acc[db][sb][r]);
      int srow = sb * 16 + l15;
      *(s16x4*)((char*)&sQ[srow][0] + (((d0w + db * 16 + lg * 4) * 2) ^ ((srow & 7) << 4))) =
          *(s16x4*)pk;
    }
  __syncthreads();
  ushort_t* qrow = Q + ((size_t)(b * 4 + h) * S_TOT + st * 64 + si) * 128 + wid * 32;
#pragma unroll
  for (int j = 0; j < 4; j++) {
    s16x8 v = *(const s16x8*)((const char*)&sQ[si][0] + ((wid * 64 + j * 16) ^ ((si & 7) << 4)));
    *(s16x8*)(qrow + j * 8) = v;
  }
}

// ---------------------------------------------------------------------------
// K4: KV build as MFMA GEMM + fused k_rope. grid B*64*4. block 256 = 4 waves.
__global__ __launch_bounds__(256) void k_gkv(
    const float* __restrict__ y_kv, const float* __restrict__ coef,
    const ushort_t* __restrict__ wkvup, const float* __restrict__ kvup_b,
    ushort_t* __restrict__ K, ushort_t* __restrict__ VT) {
  const int id = blockIdx.x;
  const int h = id & 3, st = (id >> 2) & 63, b = id >> 8;
  const int t = threadIdx.x, si = t & 63, wid = t >> 6;
  const int l15 = t & 15, lg = (t >> 4) & 3;
  const float* cf = coef + b * 320;
  __shared__ __align__(16) ushort_t Xt[64][64];
  __shared__ __align__(16) ushort_t sK[64][64];
  {
#pragma unroll
    for (int half = 0; half < 2; half++) {
      ushort_t pk[8];
#pragma unroll
      for (int j = 0; j < 8; j++) {
        int c2 = wid * 16 + half * 8 + j;
        float v = y_kv[(size_t)(b * 128 + 64 + c2) * S_TOT + st * 64 + si];
        pk[j] = f2b(v * cf[192 + c2] + cf[256 + c2]);
      }
      *(s16x8*)((char*)&Xt[si][0] + ((wid * 32 + half * 16) ^ ((si & 7) << 4))) = *(s16x8*)pk;
    }
  }
  __syncthreads();
  const int d0w = wid * 32;
  f32x4 acc[2][4];
#pragma unroll
  for (int db = 0; db < 2; db++) {
    f32x4 bv;
#pragma unroll
    for (int r = 0; r < 4; r++) bv[r] = kvup_b[h * 128 + d0w + db * 16 + lg * 4 + r];
#pragma unroll
    for (int sb = 0; sb < 4; sb++) acc[db][sb] = bv;
  }
  s16x8 wf[2][2];
#pragma unroll
  for (int db = 0; db < 2; db++)
#pragma unroll
    for (int kk = 0; kk < 2; kk++)
      wf[db][kk] = *(const s16x8*)(wkvup + (size_t)(h * 128 + d0w + db * 16 + l15) * 64 +
                                   kk * 32 + lg * 8);
#pragma unroll
  for (int sb = 0; sb < 4; sb++) {
#pragma unroll
    for (int kk = 0; kk < 2; kk++) {
      s16x8 xf = *(const s16x8*)((const char*)&Xt[sb * 16 + l15][0] +
                                 ((kk * 64 + lg * 16) ^ ((l15 & 7) << 4)));
#pragma unroll
      for (int db = 0; db < 2; db++)
        acc[db][sb] = __builtin_amdgcn_mfma_f32_16x16x32_bf16(wf[db][kk], xf, acc[db][sb], 0, 0, 0);
    }
  }
  if (wid < 2) {
#pragma unroll
    for (int db = 0; db < 2; db++)
#pragma unroll
      for (int sb = 0; sb < 4; sb++) {
        ushort_t pk[4];
#pragma unroll
        for (int r = 0; r < 4; r++) pk[r] = f2b(acc[db][sb][r]);
        int srow = sb * 16 + l15;
        *(s16x4*)((char*)&sK[srow][0] + (((d0w + db * 16 + lg * 4) * 2) ^ ((srow & 7) << 4))) =
            *(s16x4*)pk;
      }
  } else {
    ushort_t* vb = VT + (size_t)(b * 4 + h) * 64 * S_TOT;
#pragma unroll
    for (int db = 0; db < 2; db++)
#pragma unroll
      for (int sb = 0; sb < 4; sb++) {
        int sp = st * 64 + sb * 16 + l15;
#pragma unroll
        for (int r = 0; r < 4; r++) {
          int vd = (wid - 2) * 32 + db * 16 + lg * 4 + r;
          vb[(size_t)vd * S_TOT + sp] = f2b(acc[db][sb][r]);
        }
      }
  }
  __syncthreads();
  const int sp = st * 64 + si;
  ushort_t* krow = K + ((size_t)(b * 4 + h) * S_TOT + sp) * 128;
#pragma unroll
  for (int j = 0; j < 2; j++) {
    s16x8 v = *(const s16x8*)((const char*)&sK[si][0] + ((wid * 32 + j * 16) ^ ((si & 7) << 4)));
    *(s16x8*)(krow + wid * 16 + j * 8) = v;
  }
  {
    const int c0 = wid * 16, hi = sp >> 6, wi = sp & 63;
    float v[16];
#pragma unroll
    for (int j = 0; j < 16; j++) {
      int c = c0 + j;
      v[j] = y_kv[(size_t)(b * 128 + c) * S_TOT + sp] * cf[64 + c] + cf[128 + c];
    }
#pragma unroll
    for (int k = 0; k < 8; k++) {
      int p = (c0 >> 1) + k;
      rope_pair(v[2 * k], v[2 * k + 1], p, hi, wi, 1.0f);
    }
    ushort_t pk[16];
#pragma unroll
    for (int j = 0; j < 16; j++) pk[j] = f2b(v[j]);
    *(s16x8*)(krow + 64 + c0) = *(s16x8*)pk;
    *(s16x8*)(krow + 64 + c0 + 8) = *(s16x8*)(pk + 8);
  }
}

// ---------------------------------------------------------------------------
// K5: flash attention, 32x32 MFMA, QBLK=32/wave, 4 waves = 128 q/block.
// Swapped QK^T (D[kv][q]); softmax fully per-lane (q = lane&31);
// PV as O^T = V^T * P with in-register P via cvt_pk + shfl_xor(32).
// grid 512 = 2 half x 8 bh x 32 qblk. KV tile 64, dbuf LDS 48 KB.
__global__ __launch_bounds__(256, 3) void k_attn(
    const ushort_t* __restrict__ Q, const ushort_t* __restrict__ K,
    const ushort_t* __restrict__ VT, ushort_t* __restrict__ Opart,
    float* __restrict__ ml) {
  const int bid = blockIdx.x;
  const int bh = bid & 7;                  // XCD swizzle: one bh per XCD
  const int rest = bid >> 3;               // [0,64)
  const int half = rest >> 5, qblk = rest & 31;
  const int kv0 = half * 2048;
  const int tid = threadIdx.x;
  const int wid = tid >> 6, lane = tid & 63;
  const int l31 = lane & 31, hi = lane >> 5;
  const int qbase = qblk * 128 + wid * 32;
  const ushort_t* Qp = Q + (size_t)bh * S_TOT * 128;
  const ushort_t* Kp = K + (size_t)bh * S_TOT * 128;
  const ushort_t* Vp = VT + (size_t)bh * 64 * S_TOT;

  __shared__ __align__(16) ushort_t K_lds[2][64][128];  // 32 KB
  __shared__ __align__(16) ushort_t V_lds[2][64][64];   // 16 KB

  // Q B-frags: col q = l31, k(d) = chunk*16 + hi*8 + (0..7)
  s16x8 qf[8];
#pragma unroll
  for (int c = 0; c < 8; c++)
    qf[c] = *(const s16x8*)(Qp + (size_t)(qbase + l31) * 128 + c * 16 + hi * 8);

  f32x16 o0, o1;
#pragma unroll
  for (int r = 0; r < 16; r++) { o0[r] = 0.f; o1[r] = 0.f; }
  float m_s = -1e30f, l_s = 0.f;

  const int krow_l = tid >> 4;   // +i*16
  const int kcolb = (tid & 15) * 16;
  const int vrow_l = tid >> 3;   // +i*32
  const int vcolb = (tid & 7) * 16;

#define STAGE(kvb, bufi)                                                          \
  {                                                                               \
    _Pragma("unroll")                                                             \
    for (int i = 0; i < 4; i++) {                                                 \
      int row = i * 16 + krow_l;                                                  \
      int colb = kcolb ^ ((row & 15) << 4);                                       \
      gload16((const char*)(Kp + (size_t)((kvb) + row) * 128) + colb,             \
              (void*)&K_lds[bufi][i * 16 + wid * 4][0]);                          \
    }                                                                             \
    _Pragma("unroll")                                                             \
    for (int i = 0; i < 2; i++) {                                                 \
      int vd = i * 32 + vrow_l;                                                   \
      int colb = vcolb ^ ((vd & 7) << 4);                                         \
      gload16((const char*)(Vp + (size_t)vd * S_TOT + (kvb)) + colb,              \
              (void*)&V_lds[bufi][i * 32 + wid * 8][0]);                          \
    }                                                                             \
  }

  STAGE(kv0, 0);
  __syncthreads();

  const int kswz = (l31 & 15) << 4;
  const int vswz = (l31 & 7) << 4;
#pragma unroll 1
  for (int t = 0; t < 32; t++) {
    const int buf = t & 1;
    if (t < 31) STAGE(kv0 + (t + 1) * 64, buf ^ 1);
    // QK^T: sc0/sc1 = P[kv = sub*32 + crow(reg,hi)][q = l31]
    f32x16 sc0, sc1;
#pragma unroll
    for (int r = 0; r < 16; r++) { sc0[r] = 0.f; sc1[r] = 0.f; }
    __builtin_amdgcn_s_setprio(1);
#pragma unroll
    for (int c = 0; c < 8; c++) {
      const int off = (c * 32 + hi * 16) ^ kswz;
      s16x8 k0 = *(const s16x8*)((const char*)&K_lds[buf][l31][0] + off);
      s16x8 k1 = *(const s16x8*)((const char*)&K_lds[buf][32 + l31][0] + off);
      sc0 = __builtin_amdgcn_mfma_f32_32x32x16_bf16(k0, qf[c], sc0, 0, 0, 0);
      sc1 = __builtin_amdgcn_mfma_f32_32x32x16_bf16(k1, qf[c], sc1, 0, 0, 0);
    }
    __builtin_amdgcn_s_setprio(0);
    // row max over 32 regs + partner
    float pmax;
    {
      float a = fmaxf(sc0[0], sc0[1]);
#pragma unroll
      for (int r = 2; r < 16; r++) a = fmaxf(a, sc0[r]);
#pragma unroll
      for (int r = 0; r < 16; r++) a = fmaxf(a, sc1[r]);
      pmax = a;
    }
    pmax = fmaxf(pmax, __shfl_xor(pmax, 32, 64));
    if (__any(pmax - m_s > 11.5f)) {   // defer-max
      float mn = fmaxf(m_s, pmax);
      float alpha = exp2f(m_s - mn);
      m_s = mn;
      l_s *= alpha;
#pragma unroll
      for (int r = 0; r < 16; r++) { o0[r] *= alpha; o1[r] *= alpha; }
    }
    float rs = 0.f;
#pragma unroll
    for (int r = 0; r < 16; r++) {
      float p0 = exp2f(sc0[r] - m_s);
      float p1 = exp2f(sc1[r] - m_s);
      sc0[r] = p0; sc1[r] = p1;
      rs += p0 + p1;
    }
    l_s += rs;
    // PV: per 16-kv chunk assemble P B-frag in-register, V^T A-frag from LDS
    __builtin_amdgcn_s_setprio(1);
#pragma unroll
    for (int c = 0; c < 4; c++) {
      const f32x16 P = (c < 2) ? sc0 : sc1;
      const int rA = 8 * (c & 1);
      uint_t a0 = cvt_pk_bf16(P[rA + 0], P[rA + 1]);
      uint_t a1 = cvt_pk_bf16(P[rA + 2], P[rA + 3]);
      uint_t b0 = cvt_pk_bf16(P[rA + 4], P[rA + 5]);
      uint_t b1 = cvt_pk_bf16(P[rA + 6], P[rA + 7]);
      uint_t s0 = hi ? a0 : b0, s1 = hi ? a1 : b1;
      uint_t r0 = (uint_t)__shfl_xor((int)s0, 32, 64);
      uint_t r1 = (uint_t)__shfl_xor((int)s1, 32, 64);
      union { uint_t u[4]; s16x8 v; } pf;
      pf.u[0] = hi ? r0 : a0; pf.u[1] = hi ? r1 : a1;
      pf.u[2] = hi ? b0 : r0; pf.u[3] = hi ? b1 : r1;
      const int voff = (c * 32 + hi * 16) ^ vswz;
      s16x8 v0 = *(const s16x8*)((const char*)&V_lds[buf][l31][0] + voff);
      s16x8 v1 = *(const s16x8*)((const char*)&V_lds[buf][32 + l31][0] + voff);
      o0 = __builtin_amdgcn_mfma_f32_32x32x16_bf16(v0, pf.v, o0, 0, 0, 0);
      o1 = __builtin_amdgcn_mfma_f32_32x32x16_bf16(v1, pf.v, o1, 0, 0, 0);
    }
    __builtin_amdgcn_s_setprio(0);
    __syncthreads();
  }
#undef STAGE
  // finalize l (partner holds the other 32 kv columns' partials)
  l_s += __shfl_xor(l_s, 32, 64);
  float linv = 1.f / l_s;
  if (lane < 32) {
    float* mlrow = ml + ((size_t)(half * 8 + bh) * S_TOT + qbase + l31) * 2;
    mlrow[0] = m_s; mlrow[1] = l_s;
  }
  // O^T epilogue via LDS bounce (reuse K_lds[0] = 16 KB): rows = block q, 128 B
  char* sO = (char*)&K_lds[0][0][0];
#pragma unroll
  for (int vt = 0; vt < 2; vt++) {
#pragma unroll
    for (int r = 0; r < 16; r += 2) {
      float v0 = (vt ? o1[r] : o0[r]) * linv;
      float v1 = (vt ? o1[r + 1] : o0[r + 1]) * linv;
      uint_t u = cvt_pk_bf16(v0, v1);
      int vd = vt * 32 + (r & 3) + 8 * (r >> 2) + 4 * hi;
      *(uint_t*)(sO + (wid * 32 + l31) * 128 + ((vd * 2) ^ ((l31 & 7) << 4))) = u;
    }
  }
  __syncthreads();
  {
    const int r = tid >> 1, hf = tid & 1;   // r: 128 q rows, hf: vd half
    const int w = r >> 5, ql = r & 31;
    ushort_t* orow = Opart + ((size_t)(half * 8 + bh) * S_TOT + qblk * 128 + r) * 64 + hf * 32;
#pragma unroll
    for (int j = 0; j < 4; j++) {
      s16x8 v = *(const s16x8*)(sO + (w * 32 + ql) * 128 + ((hf * 64 + j * 16) ^ ((ql & 7) << 4)));
      *(s16x8*)(orow + j * 8) = v;
    }
  }
}

// ---------------------------------------------------------------------------
// K6: out conv as MFMA GEMM with fused split-KV combine + residual.
__global__ __launch_bounds__(256) void k_oc(
    const ushort_t* __restrict__ Opart, const float* __restrict__ ml,
    const ushort_t* __restrict__ wout, const float* __restrict__ out_b,
    const float* __restrict__ x, float* __restrict__ out) {
  const int id = blockIdx.x;
  const int cch = id & 1, st32 = (id >> 1) & 127, b = id >> 8;
  const int t = threadIdx.x, wid = t >> 6;
  const int l15 = t & 15, lg = (t >> 4) & 3;
  __shared__ __align__(16) ushort_t Xt[32][256];
  {
    const int s = t & 31, grp = t >> 5;
    const int h = grp >> 1, vd0 = (grp & 1) * 32;
    const int sp = st32 * 32 + s;
    const float2 ml0 = *(const float2*)&ml[((size_t)(b * 4 + h) * S_TOT + sp) * 2];
    const float2 ml1 = *(const float2*)&ml[((size_t)(8 + b * 4 + h) * S_TOT + sp) * 2];
    float mm = fmaxf(ml0.x, ml1.x);
    float w0 = exp2f(ml0.x - mm) * ml0.y, w1 = exp2f(ml1.x - mm) * ml1.y;
    float inv = 1.f / (w0 + w1);
    w0 *= inv; w1 *= inv;
    const ushort_t* oa = Opart + ((size_t)(b * 4 + h) * S_TOT + sp) * 64 + vd0;
    const ushort_t* obp = oa + (size_t)8 * S_TOT * 64;
#pragma unroll
    for (int j4 = 0; j4 < 4; j4++) {
      union { s16x8 v; ushort_t u[8]; } av, bv2;
      av.v = *(const s16x8*)(oa + j4 * 8);
      bv2.v = *(const s16x8*)(obp + j4 * 8);
      ushort_t pk[8];
#pragma unroll
      for (int j = 0; j < 8; j++) pk[j] = f2b(w0 * b2f(av.u[j]) + w1 * b2f(bv2.u[j]));
      *(s16x8*)((char*)&Xt[s][0] + ((grp * 64 + j4 * 16) ^ ((s & 7) << 4))) = *(s16x8*)pk;
    }
  }
  __syncthreads();
  const int c0w = cch * 64 + wid * 16;
  f32x4 acc[2];
  {
    f32x4 bv;
#pragma unroll
    for (int r = 0; r < 4; r++) bv[r] = out_b[c0w + lg * 4 + r];
    acc[0] = bv; acc[1] = bv;
  }
#pragma unroll
  for (int kk = 0; kk < 8; kk++) {
    s16x8 wf = *(const s16x8*)(wout + (size_t)(c0w + l15) * 256 + kk * 32 + lg * 8);
#pragma unroll
    for (int sb = 0; sb < 2; sb++) {
      s16x8 xf = *(const s16x8*)((const char*)&Xt[sb * 16 + l15][0] +
                                 ((kk * 64 + lg * 16) ^ ((l15 & 7) << 4)));
      acc[sb] = __builtin_amdgcn_mfma_f32_16x16x32_bf16(wf, xf, acc[sb], 0, 0, 0);
    }
  }
#pragma unroll
  for (int sb = 0; sb < 2; sb++) {
#pragma unroll
    for (int r = 0; r < 4; r++) {
      int c = c0w + lg * 4 + r;
      int sp = st32 * 32 + sb * 16 + l15;
      size_t idx = (size_t)(b * 128 + c) * S_TOT + sp;
      out[idx] = acc[sb][r] + x[idx];
    }
  }
}

// ---------------------------------------------------------------------------
extern "C" void kernel_launch(void* const* d_in, const int* in_sizes, int n_in,
                              void* d_out, int out_size, void* d_ws, size_t ws_size,
                              hipStream_t stream) {
  const float* x      = (const float*)d_in[0];
  const float* q1_w   = (const float*)d_in[1];
  const float* q1_b   = (const float*)d_in[2];
  const float* q_gn_g = (const float*)d_in[3];
  const float* q_gn_b = (const float*)d_in[4];
  const float* q2_w   = (const float*)d_in[5];
  const float* q2_b   = (const float*)d_in[6];
  const float* kv1_w  = (const float*)d_in[7];
  const float* kv1_b  = (const float*)d_in[8];
  const float* kv_gn_g= (const float*)d_in[9];
  const float* kv_gn_b= (const float*)d_in[10];
  const float* kvn_g  = (const float*)d_in[11];
  const float* kvn_b  = (const float*)d_in[12];
  const float* kvup_w = (const float*)d_in[13];
  const float* kvup_b = (const float*)d_in[14];
  const float* out_w  = (const float*)d_in[15];
  const float* out_b  = (const float*)d_in[16];

  const size_t MB = 1u << 20;
  char* ws = (char*)d_ws;
  float*    y_q   = (float*)(ws);                         // 0..1 MB
  float*    y_kv  = (float*)(ws + 1 * MB);                // 1..5 MB
  ushort_t* Q     = (ushort_t*)(ws + 5 * MB);             // 5..13 MB
  ushort_t* K     = (ushort_t*)(ws + 13 * MB);            // 13..21 MB
  ushort_t* VT    = (ushort_t*)(ws + 21 * MB);            // 21..25 MB
  double*   pch   = (double*)(ws + 25 * MB);              // 25..26.4 MB
  float*    coef  = (float*)(ws + 27 * MB);               // 2.5 KB
  ushort_t* wq2   = (ushort_t*)(ws + 27 * MB + 65536);    // 32 KB
  ushort_t* wkvup = (ushort_t*)(ws + 27 * MB + 131072);   // 64 KB
  ushort_t* wout  = (ushort_t*)(ws + 27 * MB + 262144);   // 64 KB
  double*   SQ    = (double*)(ws + 27 * MB + 524288);     // 5 KB
  ushort_t* Opart = (ushort_t*)(ws + 29 * MB);            // 29..37.4 MB
  float*    ml    = (float*)(ws + 38 * MB);               // 0.5 MB
  float*    out   = (float*)d_out;

  k_conv1<<<832, 256, 0, stream>>>(x, q1_w, q1_b, kv1_w, kv1_b, y_q, y_kv, pch,
                                   q2_w, kvup_w, out_w, wq2, wkvup, wout);
  k_red  <<<320, 256, 0, stream>>>(pch, SQ);
  k_stats<<<1,   512, 0, stream>>>(SQ, q_gn_g, q_gn_b, kv_gn_g, kv_gn_b, kvn_g, kvn_b, coef);
  k_gq   <<<512, 256, 0, stream>>>(y_q, coef, wq2, q2_b, Q);
  k_gkv  <<<512, 256, 0, stream>>>(y_kv, coef, wkvup, kvup_b, K, VT);
  k_attn <<<512, 256, 0, stream>>>(Q, K, VT, Opart, ml);
  k_oc   <<<512, 256, 0, stream>>>(Opart, ml, wout, out_b, x, out);
}